// Round 6
// baseline (1302.742 us; speedup 1.0000x reference)
//
#include <hip/hip_runtime.h>
#include <cstdint>

#define N_NODES 50000
#define N_EDGES 800000
#define C 64
#define B_N 96                      // nodes per bucket (6 MFMA tiles)
#define NB 521                      // ceil(N/B_N)
#define PCAP 2048                   // edge cap/bucket (mean 1536, ~13 sigma)
#define TILES 6                     // B_N/16
#define STG_BLOCKS 126
#define STG_CHUNK 6350              // 126*6350 >= E

typedef __attribute__((ext_vector_type(8))) short bf16x8;   // 8 bf16 in 4 VGPRs
typedef __attribute__((ext_vector_type(4))) float f32x4;

// ---------------- workspace layout (word units) ----------------
// Round-17: R5 col-swept structure with the bucket-index fix (r/96u exact;
// the hand-rolled magic (r*21846)>>21 overflowed for r=96q+95, q>=341,
// corrupting ~179 nodes -> absmax 0.785). Structure unchanged otherwise.
static constexpr size_t OFF_GCUR = 0;                                // 1024 ints
static constexpr size_t OFF_DINV = 1024;                             // 50176 fl
static constexpr size_t OFF_BZR  = 51200;                            // 16384 w
static constexpr size_t OFF_BH   = 67584;                            // 8192 w
static constexpr size_t OFF_CSE  = 75776;                            // NB*PCAP uint2 = 2,134,016 w
static constexpr size_t OFF_XH   = OFF_CSE + (size_t)NB * PCAP * 2;  // N*C uints
static constexpr size_t OFF_XB   = OFF_XH + (size_t)N_NODES * C;     // N*C/2 w
static constexpr size_t OFF_HB   = OFF_XB + (size_t)N_NODES * C / 2;
static constexpr size_t OFF_PXB  = OFF_HB + (size_t)N_NODES * C / 2;
static constexpr size_t OFF_RHB  = OFF_PXB + (size_t)N_NODES * C / 2;
static constexpr size_t OFF_RHD  = OFF_RHB + (size_t)N_NODES * C / 2;
// stg (K2 staging) aliases PXB..: needs 2*NB*PCAP = 2,134,016 w < 3.2M there.
static constexpr size_t OFF_STG  = OFF_PXB;
// end = OFF_RHD + N*C/2 = 13,409,792 words = 53.6 MB (< 64.5 MB proven OK)

__device__ __forceinline__ short f2bf(float f) {             // RNE fp32 -> bf16
    unsigned u = __float_as_uint(f);
    u += 0x7fffu + ((u >> 16) & 1u);
    return (short)(u >> 16);
}
__device__ __forceinline__ float bf_lo(unsigned v) { return __uint_as_float(v << 16); }
__device__ __forceinline__ float bf_hi(unsigned v) { return __uint_as_float(v & 0xffff0000u); }
__device__ __forceinline__ float bfu(unsigned short v) { return __uint_as_float((unsigned)v << 16); }
__device__ __forceinline__ float fast_sigmoid(float v) { return 1.f / (1.f + __expf(-v)); }
__device__ __forceinline__ float fast_tanh(float v) { return 1.f - 2.f / (__expf(2.f * v) + 1.f); }
__device__ __forceinline__ bf16x8 pack_bf8(f32x4 a, f32x4 b) {
    short t[8];
    t[0] = f2bf(a[0]); t[1] = f2bf(a[1]); t[2] = f2bf(a[2]); t[3] = f2bf(a[3]);
    t[4] = f2bf(b[0]); t[5] = f2bf(b[1]); t[6] = f2bf(b[2]); t[7] = f2bf(b[3]);
    return *(bf16x8*)t;
}

// ======================= K1: zero gcur + weight pack =======================
__global__ __launch_bounds__(256) void zero_pack_kernel(
        int* __restrict__ gcur,
        const float* __restrict__ Wz, const float* __restrict__ Wr,
        const float* __restrict__ Wh,
        short* __restrict__ Bzr, short* __restrict__ Bh) {
    if (blockIdx.x == 24) {
        gcur[threadIdx.x] = 0;
        gcur[256 + threadIdx.x] = 0;
        gcur[512 + threadIdx.x] = 0;
        return;
    }
    int gid = blockIdx.x * 256 + threadIdx.x;           // < 6144
    if (gid < 4096) {                                   // zr: 64 (kt,ct) x 64 lanes
        int ktct = gid >> 6, lane = gid & 63;
        int kt = ktct >> 3, ct = ktct & 7;
        int colg = ct * 16 + (lane & 15);
        int k0 = kt * 32 + (lane >> 4) * 8;
        const float* W = (colg < 64) ? Wz : Wr;
        int c = colg & 63;
        short v[8];
        #pragma unroll
        for (int j = 0; j < 8; ++j) {
            int k = k0 + j;
            v[j] = f2bf(W[(k >> 7) * (128 * 64) + (k & 127) * 64 + c]);
        }
        *(bf16x8*)(Bzr + (size_t)ktct * 512 + lane * 8) = *(bf16x8*)v;
    } else {                                            // h: 32 (kt,ct) x 64 lanes
        int idx = gid - 4096;
        int ktct = idx >> 6, lane = idx & 63;
        int kt = ktct >> 2, ct = ktct & 3;
        int colg = ct * 16 + (lane & 15);
        int k0 = kt * 32 + (lane >> 4) * 8;
        short v[8];
        #pragma unroll
        for (int j = 0; j < 8; ++j) {
            int k = k0 + j;
            v[j] = f2bf(Wh[(k >> 7) * (128 * 64) + (k & 127) * 64 + colg]);
        }
        *(bf16x8*)(Bh + (size_t)ktct * 512 + lane * 8) = *(bf16x8*)v;
    }
}

// ======================= K2: stage edges into coarse buckets =======================
__global__ __launch_bounds__(512) void stage_kernel(
        const int* __restrict__ row, const int* __restrict__ col,
        const float* __restrict__ w,
        int* __restrict__ gcur, uint2* __restrict__ stg) {
    __shared__ int lcnt[NB];
    __shared__ int lbase[NB];
    int tid = threadIdx.x;
    int e0 = blockIdx.x * STG_CHUNK;
    int e1 = min(e0 + STG_CHUNK, N_EDGES);
    for (int i = tid; i < NB; i += 512) lcnt[i] = 0;
    __syncthreads();
    for (int e = e0 + tid; e < e1; e += 512)
        atomicAdd(&lcnt[(unsigned)row[e] / 96u], 1);
    __syncthreads();
    for (int i = tid; i < NB; i += 512) {
        int c = lcnt[i];
        lbase[i] = c ? atomicAdd(&gcur[i], c) : 0;
        lcnt[i] = 0;
    }
    __syncthreads();
    for (int e = e0 + tid; e < e1; e += 512) {
        unsigned r = (unsigned)row[e];
        unsigned b = r / 96u;
        int off = atomicAdd(&lcnt[b], 1);
        int pos = lbase[b] + off;
        unsigned cw = ((unsigned)col[e] << 16) | (unsigned short)f2bf(w[e]);
        if (pos < PCAP)
            stg[(size_t)b * PCAP + pos] = make_uint2(r - b * B_N, cw);
    }
}

// ======================= K3: col-sort -> cse + dinv + feature pack =====
// Counting-sort bucket's edges by col>>8 (196 bins) so K4/K5 process them in
// ~ascending col order (all blocks sweep together -> cache-hot gathers).
__global__ __launch_bounds__(256) void sort_kernel(
        const int* __restrict__ gcur, const uint2* __restrict__ stg,
        const float* __restrict__ x, const float* __restrict__ h,
        unsigned* __restrict__ cse, float* __restrict__ dinv,
        unsigned* __restrict__ xh,
        unsigned short* __restrict__ xb, unsigned short* __restrict__ hb) {
    __shared__ float ldeg[B_N];
    __shared__ float ldv[B_N];
    __shared__ int bins[256];
    __shared__ int scanb[256];
    __shared__ unsigned lbuf[PCAP];
    __shared__ unsigned char lnode[PCAP];
    int b = blockIdx.x, tid = threadIdx.x;
    int n0 = b * B_N;
    int m = min(gcur[b], PCAP);
    if (tid < B_N) ldeg[tid] = 0.f;
    bins[tid] = 0;
    __syncthreads();
    const uint2* s = stg + (size_t)b * PCAP;
    for (int i = tid; i < m; i += 256) {              // deg + col histogram
        uint2 e = s[i];
        atomicAdd(&ldeg[e.x], bf_lo(e.y));
        atomicAdd(&bins[e.y >> 24], 1);               // bin = col>>8 (<196)
    }
    __syncthreads();
    scanb[tid] = bins[tid];                           // inclusive scan over 256
    __syncthreads();
    for (int d = 1; d < 256; d <<= 1) {
        int v = (tid >= d) ? scanb[tid - d] : 0;
        __syncthreads();
        scanb[tid] += v;
        __syncthreads();
    }
    int base_excl = scanb[tid] - bins[tid];
    __syncthreads();
    scanb[tid] = base_excl;
    bins[tid] = 0;
    __syncthreads();
    for (int i = tid; i < m; i += 256) {              // scatter by col bin
        uint2 e = s[i];
        int bin = e.y >> 24;
        int off = atomicAdd(&bins[bin], 1);
        int p = scanb[bin] + off;
        lbuf[p] = e.y;
        lnode[p] = (unsigned char)e.x;
    }
    __syncthreads();
    int mpad = (m + 63) & ~63;
    if (mpad == 0) mpad = 64;
    for (int i = tid; i < mpad; i += 256) {           // stream out, zero-padded
        unsigned rl = (i < m) ? (unsigned)lnode[i] : 0u;
        unsigned cw = (i < m) ? lbuf[i] : 0u;
        *(uint2*)(cse + (size_t)b * (PCAP * 2) + (size_t)i * 2) = make_uint2(rl, cw);
    }
    if (tid < B_N) {
        int node = n0 + tid;
        float d = ldeg[tid];
        float dv = (d > 0.f) ? rsqrtf(d) : 0.f;
        if (node < N_NODES) dinv[node] = dv;
        ldv[tid] = dv;
    }
    __syncthreads();
    for (int i = tid; i < B_N * 16; i += 256) {       // feature pack (float4 groups)
        int g = n0 * 16 + i;
        if (g >= N_NODES * 16) continue;
        float dv = ldv[i >> 4];
        float4 xv = ((const float4*)x)[g];
        float4 hv = ((const float4*)h)[g];
        uint4 o;
        o.x = ((unsigned)(unsigned short)f2bf(hv.x * dv) << 16) | (unsigned short)f2bf(xv.x * dv);
        o.y = ((unsigned)(unsigned short)f2bf(hv.y * dv) << 16) | (unsigned short)f2bf(xv.y * dv);
        o.z = ((unsigned)(unsigned short)f2bf(hv.z * dv) << 16) | (unsigned short)f2bf(xv.z * dv);
        o.w = ((unsigned)(unsigned short)f2bf(hv.w * dv) << 16) | (unsigned short)f2bf(xv.w * dv);
        ((uint4*)xh)[g] = o;
        ((short4*)xb)[g] = make_short4(f2bf(xv.x), f2bf(xv.y), f2bf(xv.z), f2bf(xv.w));
        ((short4*)hb)[g] = make_short4(f2bf(hv.x), f2bf(hv.y), f2bf(hv.z), f2bf(hv.w));
    }
}

// ======================= K4: col-swept prop2 + zr-GEMM =======================
// 512 thr. Phase A: 8 waves x 8 edges/iter from the col-sorted list; LDS fp32
// atomic accumulation (ds_add; 64 lanes/row = 2-way banks, free). Records
// prefetched one iter ahead; 8 value loads batched before consumes.
__global__ __launch_bounds__(512) void prop_gemm_zr_kernel(
        const int* __restrict__ gcur, const unsigned* __restrict__ cse,
        const float* __restrict__ dinv, const unsigned* __restrict__ xh,
        const unsigned short* __restrict__ xb, const unsigned short* __restrict__ hb,
        const short* __restrict__ Bzr,
        const float* __restrict__ bz, const float* __restrict__ br,
        unsigned short* __restrict__ Pxb,
        float* __restrict__ z, unsigned short* __restrict__ rhb,
        unsigned short* __restrict__ rhd) {
    __shared__ float acc[2][B_N][68];                 // fp32 accum, pad 68
    __shared__ float ldv[B_N];
    int tid = threadIdx.x;
    int wid = __builtin_amdgcn_readfirstlane(tid >> 6);
    int lane = tid & 63;
    int b = blockIdx.x;
    int node0 = b * B_N;
    for (int i = tid; i < 2 * B_N * 68; i += 512) ((float*)acc)[i] = 0.f;
    if (tid < B_N) {
        int node = node0 + tid;
        ldv[tid] = (node < N_NODES) ? -dinv[node] : 0.f;
    }
    __syncthreads();

    // ---- phase A ----
    int m = min(gcur[b], PCAP);
    int niter = (m + 63) >> 6;
    if (niter == 0) niter = 1;
    const uint4* ep = (const uint4*)(cse + (size_t)b * (PCAP * 2)) + wid * 4;
    uint4 ra = ep[0], rb = ep[1], rc = ep[2], rd = ep[3];
    for (int t = 0; t < niter; ++t) {
        unsigned v0 = xh[(ra.y >> 16) * C + lane];
        unsigned v1 = xh[(ra.w >> 16) * C + lane];
        unsigned v2 = xh[(rb.y >> 16) * C + lane];
        unsigned v3 = xh[(rb.w >> 16) * C + lane];
        unsigned v4 = xh[(rc.y >> 16) * C + lane];
        unsigned v5 = xh[(rc.w >> 16) * C + lane];
        unsigned v6 = xh[(rd.y >> 16) * C + lane];
        unsigned v7 = xh[(rd.w >> 16) * C + lane];
        uint4 na = ra, nb2 = rb, nc = rc, nd = rd;
        if (t + 1 < niter) {
            const uint4* np = ep + (size_t)(t + 1) * 32;
            na = np[0]; nb2 = np[1]; nc = np[2]; nd = np[3];
        }
        float w0 = bf_lo(ra.y), w1 = bf_lo(ra.w);
        float w2 = bf_lo(rb.y), w3 = bf_lo(rb.w);
        float w4 = bf_lo(rc.y), w5 = bf_lo(rc.w);
        float w6 = bf_lo(rd.y), w7 = bf_lo(rd.w);
        atomicAdd(&acc[0][ra.x][lane], w0 * bf_lo(v0));
        atomicAdd(&acc[1][ra.x][lane], w0 * bf_hi(v0));
        atomicAdd(&acc[0][ra.z][lane], w1 * bf_lo(v1));
        atomicAdd(&acc[1][ra.z][lane], w1 * bf_hi(v1));
        atomicAdd(&acc[0][rb.x][lane], w2 * bf_lo(v2));
        atomicAdd(&acc[1][rb.x][lane], w2 * bf_hi(v2));
        atomicAdd(&acc[0][rb.z][lane], w3 * bf_lo(v3));
        atomicAdd(&acc[1][rb.z][lane], w3 * bf_hi(v3));
        atomicAdd(&acc[0][rc.x][lane], w4 * bf_lo(v4));
        atomicAdd(&acc[1][rc.x][lane], w4 * bf_hi(v4));
        atomicAdd(&acc[0][rc.z][lane], w5 * bf_lo(v5));
        atomicAdd(&acc[1][rc.z][lane], w5 * bf_hi(v5));
        atomicAdd(&acc[0][rd.x][lane], w6 * bf_lo(v6));
        atomicAdd(&acc[1][rd.x][lane], w6 * bf_hi(v6));
        atomicAdd(&acc[0][rd.z][lane], w7 * bf_lo(v7));
        atomicAdd(&acc[1][rd.z][lane], w7 * bf_hi(v7));
        ra = na; rb = nb2; rc = nc; rd = nd;
    }
    __syncthreads();

    // ---- convert: scale by -dinv[row]; write Pxb (bf16) for K5 ----
    for (int idx = tid; idx < B_N * 16; idx += 512) {
        int r = idx >> 4, c0 = (idx & 15) * 4;
        float sc = ldv[r];
        f32x4 va = *(f32x4*)&acc[0][r][c0];
        f32x4 vb = *(f32x4*)&acc[1][r][c0];
        va *= sc; vb *= sc;
        *(f32x4*)&acc[0][r][c0] = va;
        *(f32x4*)&acc[1][r][c0] = vb;
        int node = node0 + r;
        if (node < N_NODES)
            *(short4*)(Pxb + (size_t)node * C + c0) =
                make_short4(f2bf(va[0]), f2bf(va[1]), f2bf(va[2]), f2bf(va[3]));
    }
    __syncthreads();

    // ---- phase B: wave = ct (8 cts), 6 node tiles each ----
    int q = lane >> 4;
    int nl = lane & 15;
    const bf16x8* Bp = (const bf16x8*)Bzr;
    bf16x8 bfr[8];
    #pragma unroll
    for (int kt = 0; kt < 8; ++kt) bfr[kt] = Bp[(kt * 8 + wid) * 64 + lane];

    for (int tile = 0; tile < TILES; ++tile) {
        int nodeA = node0 + tile * 16 + nl;
        int row = tile * 16 + nl;
        f32x4 accv = (f32x4){0.f, 0.f, 0.f, 0.f};
        #pragma unroll
        for (int kt = 0; kt < 4; ++kt) {
            const unsigned short* src = (kt < 2) ? xb : hb;
            bf16x8 a = *(const bf16x8*)(src + (size_t)nodeA * C + (kt & 1) * 32 + q * 8);
            accv = __builtin_amdgcn_mfma_f32_16x16x32_bf16(a, bfr[kt], accv, 0, 0, 0);
        }
        #pragma unroll
        for (int kt = 4; kt < 8; ++kt) {
            const float* pr = &acc[kt >= 6 ? 1 : 0][row][(kt & 1) * 32 + q * 8];
            bf16x8 a = pack_bf8(*(const f32x4*)pr, *(const f32x4*)(pr + 4));
            accv = __builtin_amdgcn_mfma_f32_16x16x32_bf16(a, bfr[kt], accv, 0, 0, 0);
        }
        if (wid < 4) {                                // z columns
            int colg = wid * 16 + nl;
            float bias = bz[colg];
            #pragma unroll
            for (int r = 0; r < 4; ++r) {
                int node = node0 + tile * 16 + q * 4 + r;
                if (node < N_NODES)
                    z[(size_t)node * C + colg] = fast_sigmoid(accv[r] + bias);
            }
        } else {                                      // r columns -> rhb, rhd
            int oc = (wid - 4) * 16 + nl;
            float bias = br[oc];
            #pragma unroll
            for (int r = 0; r < 4; ++r) {
                int node = node0 + tile * 16 + q * 4 + r;
                if (node < N_NODES) {
                    float sg = fast_sigmoid(accv[r] + bias);
                    float rhv = sg * bfu(hb[(size_t)node * C + oc]);
                    float dvr = dinv[node];
                    rhb[(size_t)node * C + oc] = (unsigned short)f2bf(rhv);
                    rhd[(size_t)node * C + oc] = (unsigned short)f2bf(rhv * dvr);
                }
            }
        }
    }
}

// ======================= K5: col-swept prop1 + h-GEMM + blend =======================
__global__ __launch_bounds__(512) void prop_gemm_h_kernel(
        const int* __restrict__ gcur, const unsigned* __restrict__ cse,
        const float* __restrict__ dinv, const unsigned short* __restrict__ rhd,
        const unsigned short* __restrict__ xb, const unsigned short* __restrict__ rhb,
        const unsigned short* __restrict__ Pxb,
        const short* __restrict__ Bh, const float* __restrict__ bh,
        const float* __restrict__ z, const float* __restrict__ h,
        float* __restrict__ out) {
    __shared__ float accR[B_N][68];
    __shared__ float ldv[B_N];
    int tid = threadIdx.x;
    int wid = __builtin_amdgcn_readfirstlane(tid >> 6);
    int lane = tid & 63;
    int b = blockIdx.x;
    int node0 = b * B_N;
    for (int i = tid; i < B_N * 68; i += 512) ((float*)accR)[i] = 0.f;
    if (tid < B_N) {
        int node = node0 + tid;
        ldv[tid] = (node < N_NODES) ? -dinv[node] : 0.f;
    }
    __syncthreads();

    // ---- phase A ----
    int m = min(gcur[b], PCAP);
    int niter = (m + 63) >> 6;
    if (niter == 0) niter = 1;
    const uint4* ep = (const uint4*)(cse + (size_t)b * (PCAP * 2)) + wid * 4;
    uint4 ra = ep[0], rb = ep[1], rc = ep[2], rd = ep[3];
    for (int t = 0; t < niter; ++t) {
        unsigned short v0 = rhd[(ra.y >> 16) * C + lane];
        unsigned short v1 = rhd[(ra.w >> 16) * C + lane];
        unsigned short v2 = rhd[(rb.y >> 16) * C + lane];
        unsigned short v3 = rhd[(rb.w >> 16) * C + lane];
        unsigned short v4 = rhd[(rc.y >> 16) * C + lane];
        unsigned short v5 = rhd[(rc.w >> 16) * C + lane];
        unsigned short v6 = rhd[(rd.y >> 16) * C + lane];
        unsigned short v7 = rhd[(rd.w >> 16) * C + lane];
        uint4 na = ra, nb2 = rb, nc = rc, nd = rd;
        if (t + 1 < niter) {
            const uint4* np = ep + (size_t)(t + 1) * 32;
            na = np[0]; nb2 = np[1]; nc = np[2]; nd = np[3];
        }
        atomicAdd(&accR[ra.x][lane], bf_lo(ra.y) * bfu(v0));
        atomicAdd(&accR[ra.z][lane], bf_lo(ra.w) * bfu(v1));
        atomicAdd(&accR[rb.x][lane], bf_lo(rb.y) * bfu(v2));
        atomicAdd(&accR[rb.z][lane], bf_lo(rb.w) * bfu(v3));
        atomicAdd(&accR[rc.x][lane], bf_lo(rc.y) * bfu(v4));
        atomicAdd(&accR[rc.z][lane], bf_lo(rc.w) * bfu(v5));
        atomicAdd(&accR[rd.x][lane], bf_lo(rd.y) * bfu(v6));
        atomicAdd(&accR[rd.z][lane], bf_lo(rd.w) * bfu(v7));
        ra = na; rb = nb2; rc = nc; rd = nd;
    }
    __syncthreads();

    // ---- convert: scale by -dinv[row] (in place) ----
    for (int idx = tid; idx < B_N * 16; idx += 512) {
        int r = idx >> 4, c0 = (idx & 15) * 4;
        f32x4 v = *(f32x4*)&accR[r][c0];
        v *= ldv[r];
        *(f32x4*)&accR[r][c0] = v;
    }
    __syncthreads();

    // ---- phase B: wave w -> ct = w&3, tiles [ (w>>2)*3, +3 ) ----
    int q = lane >> 4;
    int nl = lane & 15;
    int ct = wid & 3;
    int t0 = (wid >> 2) * 3;
    const bf16x8* Bp = (const bf16x8*)Bh;
    bf16x8 bfr[8];
    #pragma unroll
    for (int kt = 0; kt < 8; ++kt) bfr[kt] = Bp[(kt * 4 + ct) * 64 + lane];

    for (int tile = t0; tile < t0 + 3; ++tile) {
        int nodeA = node0 + tile * 16 + nl;
        int row = tile * 16 + nl;
        f32x4 accv = (f32x4){0.f, 0.f, 0.f, 0.f};
        #pragma unroll
        for (int kt = 0; kt < 6; ++kt) {
            const unsigned short* src = (kt < 2) ? xb : (kt < 4) ? rhb : Pxb;
            bf16x8 a = *(const bf16x8*)(src + (size_t)nodeA * C + (kt & 1) * 32 + q * 8);
            accv = __builtin_amdgcn_mfma_f32_16x16x32_bf16(a, bfr[kt], accv, 0, 0, 0);
        }
        #pragma unroll
        for (int kt = 6; kt < 8; ++kt) {
            const float* pr = &accR[row][(kt & 1) * 32 + q * 8];
            bf16x8 a = pack_bf8(*(const f32x4*)pr, *(const f32x4*)(pr + 4));
            accv = __builtin_amdgcn_mfma_f32_16x16x32_bf16(a, bfr[kt], accv, 0, 0, 0);
        }
        int oc = ct * 16 + nl;
        float bias = bh[oc];
        #pragma unroll
        for (int r = 0; r < 4; ++r) {
            int node = node0 + tile * 16 + q * 4 + r;
            if (node < N_NODES) {
                float ht = fast_tanh(accv[r] + bias);
                float zz = z[(size_t)node * C + oc];
                float hv = h[(size_t)node * C + oc];
                out[(size_t)node * C + oc] = (1.f - zz) * hv + zz * ht;
            }
        }
    }
}

extern "C" void kernel_launch(void* const* d_in, const int* in_sizes, int n_in,
                              void* d_out, int out_size, void* d_ws, size_t ws_size,
                              hipStream_t stream) {
    const float* x    = (const float*)d_in[0];
    const int*   eidx = (const int*)  d_in[1];
    const float* w    = (const float*)d_in[2];
    const float* h    = (const float*)d_in[3];
    const float* Wz   = (const float*)d_in[4];
    const float* bz   = (const float*)d_in[5];
    const float* Wr   = (const float*)d_in[6];
    const float* br   = (const float*)d_in[7];
    const float* Wh   = (const float*)d_in[8];
    const float* bh   = (const float*)d_in[9];
    float* out = (float*)d_out;
    float* ws  = (float*)d_ws;

    const int* row = eidx;
    const int* col = eidx + N_EDGES;

    int*            gcur = (int*)(ws + OFF_GCUR);
    float*          dinv = ws + OFF_DINV;
    short*          Bzr  = (short*)(ws + OFF_BZR);
    short*          Bh   = (short*)(ws + OFF_BH);
    unsigned*       cse  = (unsigned*)(ws + OFF_CSE);
    unsigned*       xh   = (unsigned*)(ws + OFF_XH);
    unsigned short* xb   = (unsigned short*)(ws + OFF_XB);
    unsigned short* hb   = (unsigned short*)(ws + OFF_HB);
    unsigned short* Pxb  = (unsigned short*)(ws + OFF_PXB);
    unsigned short* rhb  = (unsigned short*)(ws + OFF_RHB);
    unsigned short* rhd  = (unsigned short*)(ws + OFF_RHD);
    uint2*          stg  = (uint2*)(ws + OFF_STG);            // aliases Pxb/rhb region
    float*          z    = out;                  // z lives in d_out until K5

    // K1: pack weights + zero gcur
    zero_pack_kernel<<<25, 256, 0, stream>>>(gcur, Wz, Wr, Wh, Bzr, Bh);

    // K2: stage edges into row buckets (coalesced run-writes)
    stage_kernel<<<STG_BLOCKS, 512, 0, stream>>>(row, col, w, gcur, stg);

    // K3: col-sort buckets -> cse + dinv + xh/xb/hb
    sort_kernel<<<NB, 256, 0, stream>>>(gcur, stg, x, h, cse, dinv, xh, xb, hb);

    // K4: col-swept Lhat@[x|h] + zr GEMM (stg dead now; writes Pxb, z, rhb, rhd)
    prop_gemm_zr_kernel<<<NB, 512, 0, stream>>>(
        gcur, cse, dinv, xh, xb, hb, Bzr, bz, br, Pxb, z, rhb, rhd);

    // K5: col-swept Lhat@(r*h) + candidate GEMM + GRU blend
    prop_gemm_h_kernel<<<NB, 512, 0, stream>>>(
        gcur, cse, dinv, rhd, xb, rhb, Pxb, Bh, bh, z, h, out);
}

// Round 7
// 209.082 us; speedup vs baseline: 6.2308x; 6.2308x over previous
//
#include <hip/hip_runtime.h>
#include <cstdint>

#define N_NODES 50000
#define N_EDGES 800000
#define C 64
#define SLOTS 64                    // fixed CSR slots/node (deg~Bin: mean 16, max ~40)
#define B_N 120                     // nodes per coarse bucket
#define NB 417                      // ceil(N/B_N)
#define PCAP 2560                   // staging cap/bucket (mean 1918, ~14 sigma)
#define STG_BLOCKS 126
#define STG_CHUNK 6350              // 126*6350 >= E

typedef __attribute__((ext_vector_type(8))) short bf16x8;   // 8 bf16 in 4 VGPRs
typedef __attribute__((ext_vector_type(4))) float f32x4;

// ---------------- workspace layout (word units) ----------------
// Round-18: R2 champion structure; gather uses wide loads (dwordx4 = 4 edges
// per VMEM instruction, 16 lanes/row) + scalar csr loads -> 4x fewer
// outstanding-queue slots per edge. Layout = R2's.
static constexpr size_t OFF_GCUR = 0;                                // 512 ints
static constexpr size_t OFF_DINV = 512;                              // 50176 fl
static constexpr size_t OFF_CNT  = 50688;                            // 50176 ints
static constexpr size_t OFF_BZR  = 100864;                           // 16384 fl
static constexpr size_t OFF_BH   = 117248;                           // 8192 fl
static constexpr size_t OFF_CSR  = 125440;                           // N*64 uints = 3.2M
static constexpr size_t OFF_XH   = OFF_CSR + (size_t)N_NODES * 64;   // N*C uints
static constexpr size_t OFF_XB   = OFF_XH + (size_t)N_NODES * C;     // N*C ushort
static constexpr size_t OFF_HB   = OFF_XB + (size_t)N_NODES * C / 2;
static constexpr size_t OFF_PXB  = OFF_HB + (size_t)N_NODES * C / 2;
static constexpr size_t OFF_PHB  = OFF_PXB + (size_t)N_NODES * C / 2; // dead (stg alias only)
static constexpr size_t OFF_RHB  = OFF_PHB + (size_t)N_NODES * C / 2;
static constexpr size_t OFF_RHD  = OFF_RHB + (size_t)N_NODES * C / 2;
static constexpr size_t OFF_STG  = OFF_PXB;          // uint2; byte off %8==0
// end = OFF_RHD + N*C/2 = 16,125,440 words = 64.5 MB (<= 67.4 MB proven in r0)

__device__ __forceinline__ short f2bf(float f) {             // RNE fp32 -> bf16
    unsigned u = __float_as_uint(f);
    u += 0x7fffu + ((u >> 16) & 1u);
    return (short)(u >> 16);
}
__device__ __forceinline__ float bf_lo(unsigned v) { return __uint_as_float(v << 16); }
__device__ __forceinline__ float bf_hi(unsigned v) { return __uint_as_float(v & 0xffff0000u); }
__device__ __forceinline__ float bfu(unsigned short v) { return __uint_as_float((unsigned)v << 16); }
__device__ __forceinline__ float fast_sigmoid(float v) { return 1.f / (1.f + __expf(-v)); }
__device__ __forceinline__ float fast_tanh(float v) { return 1.f - 2.f / (__expf(2.f * v) + 1.f); }
__device__ __forceinline__ unsigned sel4u(unsigned a, unsigned b, unsigned c,
                                          unsigned d, int g) {
    unsigned r = (g & 1) ? b : a;
    unsigned s = (g & 1) ? d : c;
    return (g & 2) ? s : r;
}

// ======================= K1: zero gcur + weight pack =======================
__global__ __launch_bounds__(256) void zero_pack_kernel(
        int* __restrict__ gcur,
        const float* __restrict__ Wz, const float* __restrict__ Wr,
        const float* __restrict__ Wh,
        short* __restrict__ Bzr, short* __restrict__ Bh) {
    if (blockIdx.x == 24) {
        gcur[threadIdx.x] = 0;
        gcur[256 + threadIdx.x] = 0;
        return;
    }
    int gid = blockIdx.x * 256 + threadIdx.x;           // < 6144
    if (gid < 4096) {                                   // zr: 64 (kt,ct) x 64 lanes
        int ktct = gid >> 6, lane = gid & 63;
        int kt = ktct >> 3, ct = ktct & 7;
        int colg = ct * 16 + (lane & 15);
        int k0 = kt * 32 + (lane >> 4) * 8;
        const float* W = (colg < 64) ? Wz : Wr;
        int c = colg & 63;
        short v[8];
        #pragma unroll
        for (int j = 0; j < 8; ++j) {
            int k = k0 + j;
            v[j] = f2bf(W[(k >> 7) * (128 * 64) + (k & 127) * 64 + c]);
        }
        *(bf16x8*)(Bzr + (size_t)ktct * 512 + lane * 8) = *(bf16x8*)v;
    } else {                                            // h: 32 (kt,ct) x 64 lanes
        int idx = gid - 4096;
        int ktct = idx >> 6, lane = idx & 63;
        int kt = ktct >> 2, ct = ktct & 3;
        int colg = ct * 16 + (lane & 15);
        int k0 = kt * 32 + (lane >> 4) * 8;
        short v[8];
        #pragma unroll
        for (int j = 0; j < 8; ++j) {
            int k = k0 + j;
            v[j] = f2bf(Wh[(k >> 7) * (128 * 64) + (k & 127) * 64 + colg]);
        }
        *(bf16x8*)(Bh + (size_t)ktct * 512 + lane * 8) = *(bf16x8*)v;
    }
}

// ======================= K2: stage edges into coarse buckets =======================
__global__ __launch_bounds__(512) void stage_kernel(
        const int* __restrict__ row, const int* __restrict__ col,
        const float* __restrict__ w,
        int* __restrict__ gcur, uint2* __restrict__ stg) {
    __shared__ int lcnt[NB];
    __shared__ int lbase[NB];
    int tid = threadIdx.x;
    int e0 = blockIdx.x * STG_CHUNK;
    int e1 = min(e0 + STG_CHUNK, N_EDGES);
    for (int i = tid; i < NB; i += 512) lcnt[i] = 0;
    __syncthreads();
    for (int e = e0 + tid; e < e1; e += 512)
        atomicAdd(&lcnt[row[e] / B_N], 1);
    __syncthreads();
    for (int i = tid; i < NB; i += 512) {
        int c = lcnt[i];
        lbase[i] = c ? atomicAdd(&gcur[i], c) : 0;
        lcnt[i] = 0;
    }
    __syncthreads();
    for (int e = e0 + tid; e < e1; e += 512) {
        int r = row[e];
        int b = r / B_N;
        int off = atomicAdd(&lcnt[b], 1);
        int pos = lbase[b] + off;
        unsigned cw = ((unsigned)col[e] << 16) | (unsigned short)f2bf(w[e]);
        if (pos < PCAP)
            stg[(size_t)b * PCAP + pos] = make_uint2((unsigned)(r - b * B_N), cw);
    }
}

// ======================= K3: bucket-sort -> slot-CSR + cnt/dinv + feature pack =====
__global__ __launch_bounds__(256) void sort_kernel(
        const int* __restrict__ gcur, const uint2* __restrict__ stg,
        const float* __restrict__ x, const float* __restrict__ h,
        unsigned* __restrict__ csr, int* __restrict__ cnt, float* __restrict__ dinv,
        unsigned* __restrict__ xh,
        unsigned short* __restrict__ xb, unsigned short* __restrict__ hb) {
    __shared__ int lcnt[B_N];
    __shared__ int lbase[B_N];
    __shared__ float ldeg[B_N];
    __shared__ float ldv[B_N];
    __shared__ int scanb[128];
    __shared__ unsigned lbuf[PCAP];
    __shared__ unsigned char lnode[PCAP];
    int b = blockIdx.x, tid = threadIdx.x;
    int n0 = b * B_N;
    int m = min(gcur[b], PCAP);
    for (int i = tid; i < B_N; i += 256) { lcnt[i] = 0; ldeg[i] = 0.f; }
    __syncthreads();
    const uint2* s = stg + (size_t)b * PCAP;
    for (int i = tid; i < m; i += 256) {             // pass 1: per-node count + deg
        uint2 e = s[i];
        atomicAdd(&lcnt[e.x], 1);
        atomicAdd(&ldeg[e.x], bf_lo(e.y));
    }
    __syncthreads();
    if (tid < 128) scanb[tid] = (tid < B_N) ? lcnt[tid] : 0;   // inclusive scan (128)
    __syncthreads();
    for (int d = 1; d < 128; d <<= 1) {
        int v = 0;
        if (tid < 128 && tid >= d) v = scanb[tid - d];
        __syncthreads();
        if (tid < 128) scanb[tid] += v;
        __syncthreads();
    }
    if (tid < B_N) { lbase[tid] = scanb[tid] - lcnt[tid]; lcnt[tid] = 0; }
    __syncthreads();
    for (int i = tid; i < m; i += 256) {             // pass 2: LDS scatter (sorted)
        uint2 e = s[i];
        int off = atomicAdd(&lcnt[e.x], 1);
        int p = lbase[e.x] + off;
        lbuf[p] = e.y;
        lnode[p] = (unsigned char)e.x;
    }
    __syncthreads();
    for (int i = tid; i < m; i += 256) {             // stream out, coalesced per node
        int nl = lnode[i];
        int pos = i - lbase[nl];
        csr[(size_t)(n0 + nl) * SLOTS + pos] = lbuf[i];
    }
    // zero-fill csr tails to a multiple of 8 slots; ALWAYS at least one group
    for (int i = tid; i < B_N * 8; i += 256) {
        int nl = i >> 3;
        int node = n0 + nl;
        if (node >= N_NODES) continue;
        int mm = min(lcnt[nl], SLOTS);
        int pe = (mm + 7) & ~7;
        if (pe == 0) pe = 8;
        int idx = mm + (i & 7);
        if (idx < pe) csr[(size_t)node * SLOTS + idx] = 0u;
    }
    if (tid < B_N) {                                  // cnt + dinv
        int node = n0 + tid;
        if (node < N_NODES) {
            cnt[node] = lcnt[tid];
            float d = ldeg[tid];
            float dv = (d > 0.f) ? rsqrtf(d) : 0.f;
            dinv[node] = dv;
            ldv[tid] = dv;
        } else ldv[tid] = 0.f;
    }
    __syncthreads();
    for (int i = tid; i < B_N * 16; i += 256) {       // feature pack (float4 groups)
        int g = n0 * 16 + i;
        if (g >= N_NODES * 16) continue;
        float dv = ldv[i >> 4];
        float4 xv = ((const float4*)x)[g];
        float4 hv = ((const float4*)h)[g];
        uint4 o;
        o.x = ((unsigned)(unsigned short)f2bf(hv.x * dv) << 16) | (unsigned short)f2bf(xv.x * dv);
        o.y = ((unsigned)(unsigned short)f2bf(hv.y * dv) << 16) | (unsigned short)f2bf(xv.y * dv);
        o.z = ((unsigned)(unsigned short)f2bf(hv.z * dv) << 16) | (unsigned short)f2bf(xv.z * dv);
        o.w = ((unsigned)(unsigned short)f2bf(hv.w * dv) << 16) | (unsigned short)f2bf(xv.w * dv);
        ((uint4*)xh)[g] = o;
        ((short4*)xb)[g] = make_short4(f2bf(xv.x), f2bf(xv.y), f2bf(xv.z), f2bf(xv.w));
        ((short4*)hb)[g] = make_short4(f2bf(hv.x), f2bf(hv.y), f2bf(hv.z), f2bf(hv.w));
    }
}

// ======================= K4: fused prop2 + zr-GEMM =======================
// Block = 256 thr = 4 waves = 16 nodes. Phase A gather: 16 lanes cover one
// xh row via dwordx4 (4 channels/lane) -> 4 edges per VMEM instruction;
// csr/cnt/dinv are wave-uniform scalar loads. Per node: f32x4 partial accs,
// butterfly-reduced over the 4 lane-groups at the end.
__global__ __launch_bounds__(256) void prop_gemm_zr_kernel(
        const int* __restrict__ cnt, const unsigned* __restrict__ csr,
        const float* __restrict__ dinv, const unsigned* __restrict__ xh,
        const unsigned short* __restrict__ xb, const unsigned short* __restrict__ hb,
        const short* __restrict__ Bzr,
        const float* __restrict__ bz, const float* __restrict__ br,
        unsigned short* __restrict__ Pxb,
        float* __restrict__ z, unsigned short* __restrict__ rhb,
        unsigned short* __restrict__ rhd) {
    __shared__ __align__(16) unsigned short lpx[16][72];
    __shared__ __align__(16) unsigned short lph[16][72];
    int tid = threadIdx.x;
    int wid = __builtin_amdgcn_readfirstlane(tid >> 6);
    int lane = tid & 63;
    int lane15 = lane & 15;
    int g4 = lane >> 4;
    int node0 = blockIdx.x * 16;                      // 3125 blocks, exact

    // ---- phase A: gather 4 nodes per wave (2 pair rounds) ----
    #pragma unroll
    for (int i = 0; i < 2; ++i) {
        int nlA = wid * 4 + i * 2;
        int nA = node0 + nlA;
        int2 cc = *(const int2*)(cnt + nA);           // uniform -> s_load
        int gqA = (min(cc.x, SLOTS) + 7) >> 3;
        int gqB = (min(cc.y, SLOTS) + 7) >> 3;
        const uint4* sA = (const uint4*)(csr + (size_t)nA * SLOTS);
        const uint4* sB = (const uint4*)(csr + (size_t)(nA + 1) * SLOTS);
        f32x4 axA = {0.f,0.f,0.f,0.f}, ahA = {0.f,0.f,0.f,0.f};
        f32x4 axB = {0.f,0.f,0.f,0.f}, ahB = {0.f,0.f,0.f,0.f};
        int gmax = max(gqA, gqB);
        for (int g = 0; g < gmax; ++g) {
            bool doA = g < gqA, doB = g < gqB;        // wave-uniform
            uint4 a0, a1, b0, b1;
            uint4 vA0, vA1, vB0, vB1;
            unsigned eA0, eA1, eB0, eB1;
            if (doA) { a0 = sA[2 * g]; a1 = sA[2 * g + 1]; }
            if (doB) { b0 = sB[2 * g]; b1 = sB[2 * g + 1]; }
            if (doA) {
                eA0 = sel4u(a0.x, a0.y, a0.z, a0.w, g4);
                eA1 = sel4u(a1.x, a1.y, a1.z, a1.w, g4);
                vA0 = *(const uint4*)(xh + (size_t)(eA0 >> 16) * C + lane15 * 4);
                vA1 = *(const uint4*)(xh + (size_t)(eA1 >> 16) * C + lane15 * 4);
            }
            if (doB) {
                eB0 = sel4u(b0.x, b0.y, b0.z, b0.w, g4);
                eB1 = sel4u(b1.x, b1.y, b1.z, b1.w, g4);
                vB0 = *(const uint4*)(xh + (size_t)(eB0 >> 16) * C + lane15 * 4);
                vB1 = *(const uint4*)(xh + (size_t)(eB1 >> 16) * C + lane15 * 4);
            }
            if (doA) {
                float w0 = bf_lo(eA0), w1 = bf_lo(eA1);
                axA[0] = fmaf(w0, bf_lo(vA0.x), axA[0]); ahA[0] = fmaf(w0, bf_hi(vA0.x), ahA[0]);
                axA[1] = fmaf(w0, bf_lo(vA0.y), axA[1]); ahA[1] = fmaf(w0, bf_hi(vA0.y), ahA[1]);
                axA[2] = fmaf(w0, bf_lo(vA0.z), axA[2]); ahA[2] = fmaf(w0, bf_hi(vA0.z), ahA[2]);
                axA[3] = fmaf(w0, bf_lo(vA0.w), axA[3]); ahA[3] = fmaf(w0, bf_hi(vA0.w), ahA[3]);
                axA[0] = fmaf(w1, bf_lo(vA1.x), axA[0]); ahA[0] = fmaf(w1, bf_hi(vA1.x), ahA[0]);
                axA[1] = fmaf(w1, bf_lo(vA1.y), axA[1]); ahA[1] = fmaf(w1, bf_hi(vA1.y), ahA[1]);
                axA[2] = fmaf(w1, bf_lo(vA1.z), axA[2]); ahA[2] = fmaf(w1, bf_hi(vA1.z), ahA[2]);
                axA[3] = fmaf(w1, bf_lo(vA1.w), axA[3]); ahA[3] = fmaf(w1, bf_hi(vA1.w), ahA[3]);
            }
            if (doB) {
                float w0 = bf_lo(eB0), w1 = bf_lo(eB1);
                axB[0] = fmaf(w0, bf_lo(vB0.x), axB[0]); ahB[0] = fmaf(w0, bf_hi(vB0.x), ahB[0]);
                axB[1] = fmaf(w0, bf_lo(vB0.y), axB[1]); ahB[1] = fmaf(w0, bf_hi(vB0.y), ahB[1]);
                axB[2] = fmaf(w0, bf_lo(vB0.z), axB[2]); ahB[2] = fmaf(w0, bf_hi(vB0.z), ahB[2]);
                axB[3] = fmaf(w0, bf_lo(vB0.w), axB[3]); ahB[3] = fmaf(w0, bf_hi(vB0.w), ahB[3]);
                axB[0] = fmaf(w1, bf_lo(vB1.x), axB[0]); ahB[0] = fmaf(w1, bf_hi(vB1.x), ahB[0]);
                axB[1] = fmaf(w1, bf_lo(vB1.y), axB[1]); ahB[1] = fmaf(w1, bf_hi(vB1.y), ahB[1]);
                axB[2] = fmaf(w1, bf_lo(vB1.z), axB[2]); ahB[2] = fmaf(w1, bf_hi(vB1.z), ahB[2]);
                axB[3] = fmaf(w1, bf_lo(vB1.w), axB[3]); ahB[3] = fmaf(w1, bf_hi(vB1.w), ahB[3]);
            }
        }
        // butterfly reduce across the 4 lane-groups (each holds 4-channel partials)
        #pragma unroll
        for (int j = 0; j < 4; ++j) {
            axA[j] += __shfl_xor(axA[j], 16, 64); axA[j] += __shfl_xor(axA[j], 32, 64);
            ahA[j] += __shfl_xor(ahA[j], 16, 64); ahA[j] += __shfl_xor(ahA[j], 32, 64);
            axB[j] += __shfl_xor(axB[j], 16, 64); axB[j] += __shfl_xor(axB[j], 32, 64);
            ahB[j] += __shfl_xor(ahB[j], 16, 64); ahB[j] += __shfl_xor(ahB[j], 32, 64);
        }
        float2 dvp = *(const float2*)(dinv + nA);     // uniform
        if (g4 == 0) {                                // lanes 0..15 hold ch 4*l..4*l+3
            float sA1 = -dvp.x, sB1 = -dvp.y;
            short4 pxA = make_short4(f2bf(sA1 * axA[0]), f2bf(sA1 * axA[1]),
                                     f2bf(sA1 * axA[2]), f2bf(sA1 * axA[3]));
            short4 phA = make_short4(f2bf(sA1 * ahA[0]), f2bf(sA1 * ahA[1]),
                                     f2bf(sA1 * ahA[2]), f2bf(sA1 * ahA[3]));
            short4 pxB = make_short4(f2bf(sB1 * axB[0]), f2bf(sB1 * axB[1]),
                                     f2bf(sB1 * axB[2]), f2bf(sB1 * axB[3]));
            short4 phB = make_short4(f2bf(sB1 * ahB[0]), f2bf(sB1 * ahB[1]),
                                     f2bf(sB1 * ahB[2]), f2bf(sB1 * ahB[3]));
            *(short4*)(&lpx[nlA][lane15 * 4]) = pxA;
            *(short4*)(&lph[nlA][lane15 * 4]) = phA;
            *(short4*)(&lpx[nlA + 1][lane15 * 4]) = pxB;
            *(short4*)(&lph[nlA + 1][lane15 * 4]) = phB;
            *(short4*)(Pxb + (size_t)nA * C + lane15 * 4) = pxA;
            *(short4*)(Pxb + (size_t)(nA + 1) * C + lane15 * 4) = pxB;
        }
    }
    __syncthreads();

    // ---- phase B: 16 nodes x 32 cols per wave ----
    int q = lane >> 4;
    int nl = lane & 15;
    f32x4 acc[2];
    acc[0] = (f32x4){0.f, 0.f, 0.f, 0.f};
    acc[1] = (f32x4){0.f, 0.f, 0.f, 0.f};
    const bf16x8* Bp = (const bf16x8*)Bzr;
    #pragma unroll
    for (int kt = 0; kt < 8; ++kt) {
        bf16x8 a;
        if (kt < 4) {
            const unsigned short* src = (kt < 2) ? xb : hb;
            a = *(const bf16x8*)(src + (size_t)(node0 + nl) * C + (kt & 1) * 32 + q * 8);
        } else {
            const unsigned short* src = (kt < 6) ? &lpx[0][0] : &lph[0][0];
            a = *(const bf16x8*)(src + nl * 72 + (kt & 1) * 32 + q * 8);
        }
        #pragma unroll
        for (int c2 = 0; c2 < 2; ++c2) {
            int ct = wid * 2 + c2;
            bf16x8 bfr = Bp[(kt * 8 + ct) * 64 + lane];
            acc[c2] = __builtin_amdgcn_mfma_f32_16x16x32_bf16(a, bfr, acc[c2], 0, 0, 0);
        }
    }

    if (wid < 2) {                                    // z columns (ct 0..3)
        #pragma unroll
        for (int c2 = 0; c2 < 2; ++c2) {
            int colg = (wid * 2 + c2) * 16 + nl;
            float bias = bz[colg];
            #pragma unroll
            for (int r = 0; r < 4; ++r) {
                int node = node0 + q * 4 + r;
                z[(size_t)node * C + colg] = fast_sigmoid(acc[c2][r] + bias);
            }
        }
    } else {                                          // r columns (ct 4..7)
        float dv[4];
        #pragma unroll
        for (int r = 0; r < 4; ++r) dv[r] = dinv[node0 + q * 4 + r];
        #pragma unroll
        for (int c2 = 0; c2 < 2; ++c2) {
            int oc = (wid * 2 + c2 - 4) * 16 + nl;
            float bias = br[oc];
            #pragma unroll
            for (int r = 0; r < 4; ++r) {
                int node = node0 + q * 4 + r;
                float sg = fast_sigmoid(acc[c2][r] + bias);
                float rhv = sg * bfu(hb[(size_t)node * C + oc]);
                rhb[(size_t)node * C + oc] = (unsigned short)f2bf(rhv);
                rhd[(size_t)node * C + oc] = (unsigned short)f2bf(rhv * dv[r]);
            }
        }
    }
}

// ======================= K5: fused prop1 + h-GEMM + GRU blend =======================
// Same wide-load gather: dwordx2 from rhd (4 channels/lane, 4 edges/instr).
__global__ __launch_bounds__(256) void prop_gemm_h_kernel(
        const int* __restrict__ cnt, const unsigned* __restrict__ csr,
        const float* __restrict__ dinv, const unsigned short* __restrict__ rhd,
        const unsigned short* __restrict__ xb, const unsigned short* __restrict__ rhb,
        const unsigned short* __restrict__ Pxb,
        const short* __restrict__ Bh, const float* __restrict__ bh,
        const float* __restrict__ z, const float* __restrict__ h,
        float* __restrict__ out) {
    __shared__ __align__(16) unsigned short lpr[16][72];
    int tid = threadIdx.x;
    int wid = __builtin_amdgcn_readfirstlane(tid >> 6);
    int lane = tid & 63;
    int lane15 = lane & 15;
    int g4 = lane >> 4;
    int node0 = blockIdx.x * 16;

    // ---- phase A: gather 4 nodes per wave (2 pair rounds) ----
    #pragma unroll
    for (int i = 0; i < 2; ++i) {
        int nlA = wid * 4 + i * 2;
        int nA = node0 + nlA;
        int2 cc = *(const int2*)(cnt + nA);
        int gqA = (min(cc.x, SLOTS) + 7) >> 3;
        int gqB = (min(cc.y, SLOTS) + 7) >> 3;
        const uint4* sA = (const uint4*)(csr + (size_t)nA * SLOTS);
        const uint4* sB = (const uint4*)(csr + (size_t)(nA + 1) * SLOTS);
        f32x4 aA = {0.f,0.f,0.f,0.f}, aB = {0.f,0.f,0.f,0.f};
        int gmax = max(gqA, gqB);
        for (int g = 0; g < gmax; ++g) {
            bool doA = g < gqA, doB = g < gqB;
            uint4 a0, a1, b0, b1;
            uint2 vA0, vA1, vB0, vB1;
            unsigned eA0, eA1, eB0, eB1;
            if (doA) { a0 = sA[2 * g]; a1 = sA[2 * g + 1]; }
            if (doB) { b0 = sB[2 * g]; b1 = sB[2 * g + 1]; }
            if (doA) {
                eA0 = sel4u(a0.x, a0.y, a0.z, a0.w, g4);
                eA1 = sel4u(a1.x, a1.y, a1.z, a1.w, g4);
                vA0 = *(const uint2*)(rhd + (size_t)(eA0 >> 16) * C + lane15 * 4);
                vA1 = *(const uint2*)(rhd + (size_t)(eA1 >> 16) * C + lane15 * 4);
            }
            if (doB) {
                eB0 = sel4u(b0.x, b0.y, b0.z, b0.w, g4);
                eB1 = sel4u(b1.x, b1.y, b1.z, b1.w, g4);
                vB0 = *(const uint2*)(rhd + (size_t)(eB0 >> 16) * C + lane15 * 4);
                vB1 = *(const uint2*)(rhd + (size_t)(eB1 >> 16) * C + lane15 * 4);
            }
            if (doA) {
                float w0 = bf_lo(eA0), w1 = bf_lo(eA1);
                aA[0] = fmaf(w0, bf_lo(vA0.x), aA[0]);
                aA[1] = fmaf(w0, bf_hi(vA0.x), aA[1]);
                aA[2] = fmaf(w0, bf_lo(vA0.y), aA[2]);
                aA[3] = fmaf(w0, bf_hi(vA0.y), aA[3]);
                aA[0] = fmaf(w1, bf_lo(vA1.x), aA[0]);
                aA[1] = fmaf(w1, bf_hi(vA1.x), aA[1]);
                aA[2] = fmaf(w1, bf_lo(vA1.y), aA[2]);
                aA[3] = fmaf(w1, bf_hi(vA1.y), aA[3]);
            }
            if (doB) {
                float w0 = bf_lo(eB0), w1 = bf_lo(eB1);
                aB[0] = fmaf(w0, bf_lo(vB0.x), aB[0]);
                aB[1] = fmaf(w0, bf_hi(vB0.x), aB[1]);
                aB[2] = fmaf(w0, bf_lo(vB0.y), aB[2]);
                aB[3] = fmaf(w0, bf_hi(vB0.y), aB[3]);
                aB[0] = fmaf(w1, bf_lo(vB1.x), aB[0]);
                aB[1] = fmaf(w1, bf_hi(vB1.x), aB[1]);
                aB[2] = fmaf(w1, bf_lo(vB1.y), aB[2]);
                aB[3] = fmaf(w1, bf_hi(vB1.y), aB[3]);
            }
        }
        #pragma unroll
        for (int j = 0; j < 4; ++j) {
            aA[j] += __shfl_xor(aA[j], 16, 64); aA[j] += __shfl_xor(aA[j], 32, 64);
            aB[j] += __shfl_xor(aB[j], 16, 64); aB[j] += __shfl_xor(aB[j], 32, 64);
        }
        float2 dvp = *(const float2*)(dinv + nA);
        if (g4 == 0) {
            float sA1 = -dvp.x, sB1 = -dvp.y;
            short4 prA = make_short4(f2bf(sA1 * aA[0]), f2bf(sA1 * aA[1]),
                                     f2bf(sA1 * aA[2]), f2bf(sA1 * aA[3]));
            short4 prB = make_short4(f2bf(sB1 * aB[0]), f2bf(sB1 * aB[1]),
                                     f2bf(sB1 * aB[2]), f2bf(sB1 * aB[3]));
            *(short4*)(&lpr[nlA][lane15 * 4]) = prA;
            *(short4*)(&lpr[nlA + 1][lane15 * 4]) = prB;
        }
    }
    __syncthreads();

    // ---- phase B: 16 nodes x 16 cols per wave (ct = wid) ----
    int q = lane >> 4;
    int nl = lane & 15;
    f32x4 acc = (f32x4){0.f, 0.f, 0.f, 0.f};
    const bf16x8* Bp = (const bf16x8*)Bh;
    #pragma unroll
    for (int kt = 0; kt < 8; ++kt) {
        bf16x8 a;
        if (kt < 6) {
            const unsigned short* src = (kt < 2) ? xb : (kt < 4) ? rhb : Pxb;
            a = *(const bf16x8*)(src + (size_t)(node0 + nl) * C + (kt & 1) * 32 + q * 8);
        } else {
            a = *(const bf16x8*)(&lpr[0][0] + nl * 72 + (kt & 1) * 32 + q * 8);
        }
        bf16x8 bfr = Bp[(kt * 4 + wid) * 64 + lane];
        acc = __builtin_amdgcn_mfma_f32_16x16x32_bf16(a, bfr, acc, 0, 0, 0);
    }

    int oc = wid * 16 + nl;
    float bias = bh[oc];
    #pragma unroll
    for (int r = 0; r < 4; ++r) {
        int node = node0 + q * 4 + r;
        float ht = fast_tanh(acc[r] + bias);
        float zz = z[(size_t)node * C + oc];
        float hv = h[(size_t)node * C + oc];   // fp32 h for final blend accuracy
        out[(size_t)node * C + oc] = (1.f - zz) * hv + zz * ht;
    }
}

extern "C" void kernel_launch(void* const* d_in, const int* in_sizes, int n_in,
                              void* d_out, int out_size, void* d_ws, size_t ws_size,
                              hipStream_t stream) {
    const float* x    = (const float*)d_in[0];
    const int*   eidx = (const int*)  d_in[1];
    const float* w    = (const float*)d_in[2];
    const float* h    = (const float*)d_in[3];
    const float* Wz   = (const float*)d_in[4];
    const float* bz   = (const float*)d_in[5];
    const float* Wr   = (const float*)d_in[6];
    const float* br   = (const float*)d_in[7];
    const float* Wh   = (const float*)d_in[8];
    const float* bh   = (const float*)d_in[9];
    float* out = (float*)d_out;
    float* ws  = (float*)d_ws;

    const int* row = eidx;
    const int* col = eidx + N_EDGES;

    int*            gcur = (int*)(ws + OFF_GCUR);
    float*          dinv = ws + OFF_DINV;
    int*            cnt  = (int*)(ws + OFF_CNT);
    unsigned*       csr  = (unsigned*)(ws + OFF_CSR);
    short*          Bzr  = (short*)(ws + OFF_BZR);
    short*          Bh   = (short*)(ws + OFF_BH);
    unsigned*       xh   = (unsigned*)(ws + OFF_XH);
    unsigned short* xb   = (unsigned short*)(ws + OFF_XB);
    unsigned short* hb   = (unsigned short*)(ws + OFF_HB);
    unsigned short* Pxb  = (unsigned short*)(ws + OFF_PXB);
    unsigned short* rhb  = (unsigned short*)(ws + OFF_RHB);
    unsigned short* rhd  = (unsigned short*)(ws + OFF_RHD);
    uint2*          stg  = (uint2*)(ws + OFF_STG);            // aliases Pxb region
    float*          z    = out;                  // z lives in d_out until gemm_h

    // K1: pack weights + zero gcur
    zero_pack_kernel<<<25, 256, 0, stream>>>(gcur, Wz, Wr, Wh, Bzr, Bh);

    // K2: stage edges into coarse buckets (coalesced run-writes)
    stage_kernel<<<STG_BLOCKS, 512, 0, stream>>>(row, col, w, gcur, stg);

    // K3: bucket-sort -> slot-CSR + cnt/dinv + xh/xb/hb (csr tails zero-padded)
    sort_kernel<<<NB, 256, 0, stream>>>(gcur, stg, x, h, csr, cnt, dinv, xh, xb, hb);

    // K4: fused Lhat@[x|h] gather + zr GEMM (writes Pxb, z, rhb, rhd; stg dead now)
    prop_gemm_zr_kernel<<<N_NODES / 16, 256, 0, stream>>>(
        cnt, csr, dinv, xh, xb, hb, Bzr, bz, br, Pxb, z, rhb, rhd);

    // K5: fused Lhat@(r*h) gather + candidate GEMM + GRU blend
    prop_gemm_h_kernel<<<N_NODES / 16, 256, 0, stream>>>(
        cnt, csr, dinv, rhd, xb, rhb, Pxb, Bh, bh, z, h, out);
}

// Round 8
// 197.549 us; speedup vs baseline: 6.5945x; 1.0584x over previous
//
#include <hip/hip_runtime.h>
#include <cstdint>

#define N_NODES 50000
#define N_EDGES 800000
#define C 64
#define SLOTS 64                    // fixed CSR slots/node (deg~Bin: mean 16, max ~40)
#define B_N 120                     // nodes per coarse bucket
#define NB 417                      // ceil(N/B_N)
#define PCAP 2560                   // staging cap/bucket (mean 1918, ~14 sigma)
#define STG_BLOCKS 126
#define STG_CHUNK 6350              // 126*6350 >= E

typedef __attribute__((ext_vector_type(8))) short bf16x8;   // 8 bf16 in 4 VGPRs
typedef __attribute__((ext_vector_type(4))) float f32x4;
typedef __attribute__((ext_vector_type(2))) float f32x2;

// ---------------- workspace layout (word units) ----------------
// Round-19: gather tables compressed to fp8 e4m3 (HW cvt). xh8 = packed
// (x*dinv, h*dinv) fp8 pairs, 128B/row -> 2 lines/edge; rhd8 = fp8, 64B/row
// (3.2MB table, per-XCD L2-resident) -> 1 line/edge. GEMM operands stay bf16.
static constexpr size_t OFF_GCUR = 0;                                // 512 ints
static constexpr size_t OFF_DINV = 512;                              // 50176 fl
static constexpr size_t OFF_CNT  = 50688;                            // 50176 ints
static constexpr size_t OFF_BZR  = 100864;                           // 16384 w
static constexpr size_t OFF_BH   = 117248;                           // 8192 w
static constexpr size_t OFF_CSR  = 125440;                           // N*64 uints = 3.2M w
static constexpr size_t OFF_XH8  = OFF_CSR + (size_t)N_NODES * 64;   // N*C*2B = 1.6M w
static constexpr size_t OFF_XB   = OFF_XH8 + (size_t)N_NODES * C / 2; // N*C ushort
static constexpr size_t OFF_HB   = OFF_XB + (size_t)N_NODES * C / 2;
static constexpr size_t OFF_PXB  = OFF_HB + (size_t)N_NODES * C / 2;
static constexpr size_t OFF_RHB  = OFF_PXB + (size_t)N_NODES * C / 2;
static constexpr size_t OFF_RHD8 = OFF_RHB + (size_t)N_NODES * C / 2; // N*C bytes = 0.8M w
// stg aliases PXB+RHB (3.2M w, both dead during staging): needs 2,135,040 w. OK.
static constexpr size_t OFF_STG  = OFF_PXB;
// end = OFF_RHD8 + N*C/4 = 12,125,440 words = 48.5 MB (< 64.5 MB proven OK)

__device__ __forceinline__ short f2bf(float f) {             // RNE fp32 -> bf16
    unsigned u = __float_as_uint(f);
    u += 0x7fffu + ((u >> 16) & 1u);
    return (short)(u >> 16);
}
__device__ __forceinline__ float bf_lo(unsigned v) { return __uint_as_float(v << 16); }
__device__ __forceinline__ float bf_hi(unsigned v) { return __uint_as_float(v & 0xffff0000u); }
__device__ __forceinline__ float bfu(unsigned short v) { return __uint_as_float((unsigned)v << 16); }
__device__ __forceinline__ float fast_sigmoid(float v) { return 1.f / (1.f + __expf(-v)); }
__device__ __forceinline__ float fast_tanh(float v) { return 1.f - 2.f / (__expf(2.f * v) + 1.f); }
__device__ __forceinline__ unsigned sel4u(unsigned a, unsigned b, unsigned c,
                                          unsigned d, int g) {
    unsigned r = (g & 1) ? b : a;
    unsigned s = (g & 1) ? d : c;
    return (g & 2) ? s : r;
}

// ---------------- fp8 e4m3 helpers (HW cvt on gfx950; manual fallback) ------
#if defined(__has_builtin)
#if __has_builtin(__builtin_amdgcn_cvt_pk_f32_fp8) && __has_builtin(__builtin_amdgcn_cvt_pk_fp8_f32)
#define HW_FP8 1
#endif
#endif

#ifndef HW_FP8
__device__ __forceinline__ float fp8_dec1(unsigned b) {      // e4m3fn -> f32
    unsigned s = b >> 7, e = (b >> 3) & 15u, m = b & 7u;
    float v = e ? __uint_as_float(((e + 120u) << 23) | (m << 20))
                : (float)m * 0.001953125f;                   // subnormal: m*2^-9
    return s ? -v : v;
}
__device__ __forceinline__ unsigned fp8_enc1(float f) {      // f32 -> e4m3fn RNE
    float a = fabsf(f);
    unsigned s = (__float_as_uint(f) >> 31) << 7;
    if (!(a < 448.f)) return s | 0x7e;
    int msub = (int)rintf(a * 512.f);
    if (msub <= 7) return s | (unsigned)msub;
    int e; float fr = frexpf(a, &e);
    int mm = (int)rintf(fr * 16.f);
    if (mm == 16) { mm = 8; e += 1; }
    int se = e - 1 + 7;
    if (se >= 16) return s | 0x7e;
    return s | (unsigned)(se << 3) | (unsigned)(mm - 8);
}
#endif

template <int HI>
__device__ __forceinline__ f32x2 fp8x2_dec(unsigned u) {     // bytes {2H,2H+1} -> 2 f32
#ifdef HW_FP8
    return __builtin_amdgcn_cvt_pk_f32_fp8(u, HI != 0);
#else
    f32x2 r;
    r[0] = fp8_dec1((u >> (HI * 16)) & 0xffu);
    r[1] = fp8_dec1((u >> (HI * 16 + 8)) & 0xffu);
    return r;
#endif
}
__device__ __forceinline__ unsigned fp8x2_enc(float a, float b) {  // low 16 bits
#ifdef HW_FP8
    return (unsigned)__builtin_amdgcn_cvt_pk_fp8_f32(a, b, 0, false) & 0xffffu;
#else
    return fp8_enc1(a) | (fp8_enc1(b) << 8);
#endif
}

// ======================= K1: zero gcur + weight pack =======================
__global__ __launch_bounds__(256) void zero_pack_kernel(
        int* __restrict__ gcur,
        const float* __restrict__ Wz, const float* __restrict__ Wr,
        const float* __restrict__ Wh,
        short* __restrict__ Bzr, short* __restrict__ Bh) {
    if (blockIdx.x == 24) {
        gcur[threadIdx.x] = 0;
        gcur[256 + threadIdx.x] = 0;
        return;
    }
    int gid = blockIdx.x * 256 + threadIdx.x;           // < 6144
    if (gid < 4096) {                                   // zr: 64 (kt,ct) x 64 lanes
        int ktct = gid >> 6, lane = gid & 63;
        int kt = ktct >> 3, ct = ktct & 7;
        int colg = ct * 16 + (lane & 15);
        int k0 = kt * 32 + (lane >> 4) * 8;
        const float* W = (colg < 64) ? Wz : Wr;
        int c = colg & 63;
        short v[8];
        #pragma unroll
        for (int j = 0; j < 8; ++j) {
            int k = k0 + j;
            v[j] = f2bf(W[(k >> 7) * (128 * 64) + (k & 127) * 64 + c]);
        }
        *(bf16x8*)(Bzr + (size_t)ktct * 512 + lane * 8) = *(bf16x8*)v;
    } else {                                            // h: 32 (kt,ct) x 64 lanes
        int idx = gid - 4096;
        int ktct = idx >> 6, lane = idx & 63;
        int kt = ktct >> 2, ct = ktct & 3;
        int colg = ct * 16 + (lane & 15);
        int k0 = kt * 32 + (lane >> 4) * 8;
        short v[8];
        #pragma unroll
        for (int j = 0; j < 8; ++j) {
            int k = k0 + j;
            v[j] = f2bf(Wh[(k >> 7) * (128 * 64) + (k & 127) * 64 + colg]);
        }
        *(bf16x8*)(Bh + (size_t)ktct * 512 + lane * 8) = *(bf16x8*)v;
    }
}

// ======================= K2: stage edges into coarse buckets =======================
__global__ __launch_bounds__(512) void stage_kernel(
        const int* __restrict__ row, const int* __restrict__ col,
        const float* __restrict__ w,
        int* __restrict__ gcur, uint2* __restrict__ stg) {
    __shared__ int lcnt[NB];
    __shared__ int lbase[NB];
    int tid = threadIdx.x;
    int e0 = blockIdx.x * STG_CHUNK;
    int e1 = min(e0 + STG_CHUNK, N_EDGES);
    for (int i = tid; i < NB; i += 512) lcnt[i] = 0;
    __syncthreads();
    for (int e = e0 + tid; e < e1; e += 512)
        atomicAdd(&lcnt[row[e] / B_N], 1);
    __syncthreads();
    for (int i = tid; i < NB; i += 512) {
        int c = lcnt[i];
        lbase[i] = c ? atomicAdd(&gcur[i], c) : 0;
        lcnt[i] = 0;
    }
    __syncthreads();
    for (int e = e0 + tid; e < e1; e += 512) {
        int r = row[e];
        int b = r / B_N;
        int off = atomicAdd(&lcnt[b], 1);
        int pos = lbase[b] + off;
        unsigned cw = ((unsigned)col[e] << 16) | (unsigned short)f2bf(w[e]);
        if (pos < PCAP)
            stg[(size_t)b * PCAP + pos] = make_uint2((unsigned)(r - b * B_N), cw);
    }
}

// ======================= K3: bucket-sort -> slot-CSR + cnt/dinv + feature pack =====
__global__ __launch_bounds__(256) void sort_kernel(
        const int* __restrict__ gcur, const uint2* __restrict__ stg,
        const float* __restrict__ x, const float* __restrict__ h,
        unsigned* __restrict__ csr, int* __restrict__ cnt, float* __restrict__ dinv,
        unsigned* __restrict__ xh8,
        unsigned short* __restrict__ xb, unsigned short* __restrict__ hb) {
    __shared__ int lcnt[B_N];
    __shared__ int lbase[B_N];
    __shared__ float ldeg[B_N];
    __shared__ float ldv[B_N];
    __shared__ int scanb[128];
    __shared__ unsigned lbuf[PCAP];
    __shared__ unsigned char lnode[PCAP];
    int b = blockIdx.x, tid = threadIdx.x;
    int n0 = b * B_N;
    int m = min(gcur[b], PCAP);
    for (int i = tid; i < B_N; i += 256) { lcnt[i] = 0; ldeg[i] = 0.f; }
    __syncthreads();
    const uint2* s = stg + (size_t)b * PCAP;
    for (int i = tid; i < m; i += 256) {             // pass 1: per-node count + deg
        uint2 e = s[i];
        atomicAdd(&lcnt[e.x], 1);
        atomicAdd(&ldeg[e.x], bf_lo(e.y));
    }
    __syncthreads();
    if (tid < 128) scanb[tid] = (tid < B_N) ? lcnt[tid] : 0;   // inclusive scan (128)
    __syncthreads();
    for (int d = 1; d < 128; d <<= 1) {
        int v = 0;
        if (tid < 128 && tid >= d) v = scanb[tid - d];
        __syncthreads();
        if (tid < 128) scanb[tid] += v;
        __syncthreads();
    }
    if (tid < B_N) { lbase[tid] = scanb[tid] - lcnt[tid]; lcnt[tid] = 0; }
    __syncthreads();
    for (int i = tid; i < m; i += 256) {             // pass 2: LDS scatter (sorted)
        uint2 e = s[i];
        int off = atomicAdd(&lcnt[e.x], 1);
        int p = lbase[e.x] + off;
        lbuf[p] = e.y;
        lnode[p] = (unsigned char)e.x;
    }
    __syncthreads();
    for (int i = tid; i < m; i += 256) {             // stream out, coalesced per node
        int nl = lnode[i];
        int pos = i - lbase[nl];
        csr[(size_t)(n0 + nl) * SLOTS + pos] = lbuf[i];
    }
    // zero-fill csr tails to a multiple of 8 slots; ALWAYS at least one group
    for (int i = tid; i < B_N * 8; i += 256) {
        int nl = i >> 3;
        int node = n0 + nl;
        if (node >= N_NODES) continue;
        int mm = min(lcnt[nl], SLOTS);
        int pe = (mm + 7) & ~7;
        if (pe == 0) pe = 8;
        int idx = mm + (i & 7);
        if (idx < pe) csr[(size_t)node * SLOTS + idx] = 0u;
    }
    if (tid < B_N) {                                  // cnt + dinv
        int node = n0 + tid;
        if (node < N_NODES) {
            cnt[node] = lcnt[tid];
            float d = ldeg[tid];
            float dv = (d > 0.f) ? rsqrtf(d) : 0.f;
            dinv[node] = dv;
            ldv[tid] = dv;
        } else ldv[tid] = 0.f;
    }
    __syncthreads();
    for (int i = tid; i < B_N * 16; i += 256) {       // feature pack (float4 groups)
        int g = n0 * 16 + i;
        if (g >= N_NODES * 16) continue;
        float dv = ldv[i >> 4];
        float4 xv = ((const float4*)x)[g];
        float4 hv = ((const float4*)h)[g];
        // fp8 pair-pack (x*dinv, h*dinv) per channel: 4 ch -> 8 bytes
        unsigned p01 = fp8x2_enc(xv.x * dv, hv.x * dv) |
                       (fp8x2_enc(xv.y * dv, hv.y * dv) << 16);
        unsigned p23 = fp8x2_enc(xv.z * dv, hv.z * dv) |
                       (fp8x2_enc(xv.w * dv, hv.w * dv) << 16);
        ((uint2*)xh8)[g] = make_uint2(p01, p23);
        ((short4*)xb)[g] = make_short4(f2bf(xv.x), f2bf(xv.y), f2bf(xv.z), f2bf(xv.w));
        ((short4*)hb)[g] = make_short4(f2bf(hv.x), f2bf(hv.y), f2bf(hv.z), f2bf(hv.w));
    }
}

// ======================= K4: fused prop2 + zr-GEMM =======================
// Gather: 16 lanes cover one 128B fp8 row (uint2 = 4 ch of (x,h) pairs) ->
// 4 edges per VMEM instruction, 2 cache lines per edge. HW fp8 decode.
__global__ __launch_bounds__(256) void prop_gemm_zr_kernel(
        const int* __restrict__ cnt, const unsigned* __restrict__ csr,
        const float* __restrict__ dinv, const unsigned* __restrict__ xh8,
        const unsigned short* __restrict__ xb, const unsigned short* __restrict__ hb,
        const short* __restrict__ Bzr,
        const float* __restrict__ bz, const float* __restrict__ br,
        unsigned short* __restrict__ Pxb,
        float* __restrict__ z, unsigned short* __restrict__ rhb,
        unsigned char* __restrict__ rhd8) {
    __shared__ __align__(16) unsigned short lpx[16][72];
    __shared__ __align__(16) unsigned short lph[16][72];
    int tid = threadIdx.x;
    int wid = __builtin_amdgcn_readfirstlane(tid >> 6);
    int lane = tid & 63;
    int lane15 = lane & 15;
    int g4 = lane >> 4;
    int node0 = blockIdx.x * 16;                      // 3125 blocks, exact

    // ---- phase A: gather 4 nodes per wave (2 pair rounds) ----
    #pragma unroll
    for (int i = 0; i < 2; ++i) {
        int nlA = wid * 4 + i * 2;
        int nA = node0 + nlA;
        int2 cc = *(const int2*)(cnt + nA);           // uniform -> s_load
        int gqA = (min(cc.x, SLOTS) + 7) >> 3;
        int gqB = (min(cc.y, SLOTS) + 7) >> 3;
        const uint4* sA = (const uint4*)(csr + (size_t)nA * SLOTS);
        const uint4* sB = (const uint4*)(csr + (size_t)(nA + 1) * SLOTS);
        f32x4 axA = {0.f,0.f,0.f,0.f}, ahA = {0.f,0.f,0.f,0.f};
        f32x4 axB = {0.f,0.f,0.f,0.f}, ahB = {0.f,0.f,0.f,0.f};
        int gmax = max(gqA, gqB);
        for (int g = 0; g < gmax; ++g) {
            bool doA = g < gqA, doB = g < gqB;        // wave-uniform
            uint4 a0, a1, b0, b1;
            uint2 vA0, vA1, vB0, vB1;
            unsigned eA0, eA1, eB0, eB1;
            if (doA) { a0 = sA[2 * g]; a1 = sA[2 * g + 1]; }
            if (doB) { b0 = sB[2 * g]; b1 = sB[2 * g + 1]; }
            if (doA) {
                eA0 = sel4u(a0.x, a0.y, a0.z, a0.w, g4);
                eA1 = sel4u(a1.x, a1.y, a1.z, a1.w, g4);
                vA0 = *(const uint2*)(xh8 + (size_t)(eA0 >> 16) * 32 + lane15 * 2);
                vA1 = *(const uint2*)(xh8 + (size_t)(eA1 >> 16) * 32 + lane15 * 2);
            }
            if (doB) {
                eB0 = sel4u(b0.x, b0.y, b0.z, b0.w, g4);
                eB1 = sel4u(b1.x, b1.y, b1.z, b1.w, g4);
                vB0 = *(const uint2*)(xh8 + (size_t)(eB0 >> 16) * 32 + lane15 * 2);
                vB1 = *(const uint2*)(xh8 + (size_t)(eB1 >> 16) * 32 + lane15 * 2);
            }
            if (doA) {
                float w0 = bf_lo(eA0), w1 = bf_lo(eA1);
                f32x2 p;
                p = fp8x2_dec<0>(vA0.x); axA[0] = fmaf(w0, p[0], axA[0]); ahA[0] = fmaf(w0, p[1], ahA[0]);
                p = fp8x2_dec<1>(vA0.x); axA[1] = fmaf(w0, p[0], axA[1]); ahA[1] = fmaf(w0, p[1], ahA[1]);
                p = fp8x2_dec<0>(vA0.y); axA[2] = fmaf(w0, p[0], axA[2]); ahA[2] = fmaf(w0, p[1], ahA[2]);
                p = fp8x2_dec<1>(vA0.y); axA[3] = fmaf(w0, p[0], axA[3]); ahA[3] = fmaf(w0, p[1], ahA[3]);
                p = fp8x2_dec<0>(vA1.x); axA[0] = fmaf(w1, p[0], axA[0]); ahA[0] = fmaf(w1, p[1], ahA[0]);
                p = fp8x2_dec<1>(vA1.x); axA[1] = fmaf(w1, p[0], axA[1]); ahA[1] = fmaf(w1, p[1], ahA[1]);
                p = fp8x2_dec<0>(vA1.y); axA[2] = fmaf(w1, p[0], axA[2]); ahA[2] = fmaf(w1, p[1], ahA[2]);
                p = fp8x2_dec<1>(vA1.y); axA[3] = fmaf(w1, p[0], axA[3]); ahA[3] = fmaf(w1, p[1], ahA[3]);
            }
            if (doB) {
                float w0 = bf_lo(eB0), w1 = bf_lo(eB1);
                f32x2 p;
                p = fp8x2_dec<0>(vB0.x); axB[0] = fmaf(w0, p[0], axB[0]); ahB[0] = fmaf(w0, p[1], ahB[0]);
                p = fp8x2_dec<1>(vB0.x); axB[1] = fmaf(w0, p[0], axB[1]); ahB[1] = fmaf(w0, p[1], ahB[1]);
                p = fp8x2_dec<0>(vB0.y); axB[2] = fmaf(w0, p[0], axB[2]); ahB[2] = fmaf(w0, p[1], ahB[2]);
                p = fp8x2_dec<1>(vB0.y); axB[3] = fmaf(w0, p[0], axB[3]); ahB[3] = fmaf(w0, p[1], ahB[3]);
                p = fp8x2_dec<0>(vB1.x); axB[0] = fmaf(w1, p[0], axB[0]); ahB[0] = fmaf(w1, p[1], ahB[0]);
                p = fp8x2_dec<1>(vB1.x); axB[1] = fmaf(w1, p[0], axB[1]); ahB[1] = fmaf(w1, p[1], ahB[1]);
                p = fp8x2_dec<0>(vB1.y); axB[2] = fmaf(w1, p[0], axB[2]); ahB[2] = fmaf(w1, p[1], ahB[2]);
                p = fp8x2_dec<1>(vB1.y); axB[3] = fmaf(w1, p[0], axB[3]); ahB[3] = fmaf(w1, p[1], ahB[3]);
            }
        }
        // butterfly reduce across the 4 lane-groups (each holds 4-channel partials)
        #pragma unroll
        for (int j = 0; j < 4; ++j) {
            axA[j] += __shfl_xor(axA[j], 16, 64); axA[j] += __shfl_xor(axA[j], 32, 64);
            ahA[j] += __shfl_xor(ahA[j], 16, 64); ahA[j] += __shfl_xor(ahA[j], 32, 64);
            axB[j] += __shfl_xor(axB[j], 16, 64); axB[j] += __shfl_xor(axB[j], 32, 64);
            ahB[j] += __shfl_xor(ahB[j], 16, 64); ahB[j] += __shfl_xor(ahB[j], 32, 64);
        }
        float2 dvp = *(const float2*)(dinv + nA);     // uniform
        if (g4 == 0) {                                // lanes 0..15 hold ch 4*l..4*l+3
            float sA1 = -dvp.x, sB1 = -dvp.y;
            short4 pxA = make_short4(f2bf(sA1 * axA[0]), f2bf(sA1 * axA[1]),
                                     f2bf(sA1 * axA[2]), f2bf(sA1 * axA[3]));
            short4 phA = make_short4(f2bf(sA1 * ahA[0]), f2bf(sA1 * ahA[1]),
                                     f2bf(sA1 * ahA[2]), f2bf(sA1 * ahA[3]));
            short4 pxB = make_short4(f2bf(sB1 * axB[0]), f2bf(sB1 * axB[1]),
                                     f2bf(sB1 * axB[2]), f2bf(sB1 * axB[3]));
            short4 phB = make_short4(f2bf(sB1 * ahB[0]), f2bf(sB1 * ahB[1]),
                                     f2bf(sB1 * ahB[2]), f2bf(sB1 * ahB[3]));
            *(short4*)(&lpx[nlA][lane15 * 4]) = pxA;
            *(short4*)(&lph[nlA][lane15 * 4]) = phA;
            *(short4*)(&lpx[nlA + 1][lane15 * 4]) = pxB;
            *(short4*)(&lph[nlA + 1][lane15 * 4]) = phB;
            *(short4*)(Pxb + (size_t)nA * C + lane15 * 4) = pxA;
            *(short4*)(Pxb + (size_t)(nA + 1) * C + lane15 * 4) = pxB;
        }
    }
    __syncthreads();

    // ---- phase B: 16 nodes x 32 cols per wave ----
    int q = lane >> 4;
    int nl = lane & 15;
    f32x4 acc[2];
    acc[0] = (f32x4){0.f, 0.f, 0.f, 0.f};
    acc[1] = (f32x4){0.f, 0.f, 0.f, 0.f};
    const bf16x8* Bp = (const bf16x8*)Bzr;
    #pragma unroll
    for (int kt = 0; kt < 8; ++kt) {
        bf16x8 a;
        if (kt < 4) {
            const unsigned short* src = (kt < 2) ? xb : hb;
            a = *(const bf16x8*)(src + (size_t)(node0 + nl) * C + (kt & 1) * 32 + q * 8);
        } else {
            const unsigned short* src = (kt < 6) ? &lpx[0][0] : &lph[0][0];
            a = *(const bf16x8*)(src + nl * 72 + (kt & 1) * 32 + q * 8);
        }
        #pragma unroll
        for (int c2 = 0; c2 < 2; ++c2) {
            int ct = wid * 2 + c2;
            bf16x8 bfr = Bp[(kt * 8 + ct) * 64 + lane];
            acc[c2] = __builtin_amdgcn_mfma_f32_16x16x32_bf16(a, bfr, acc[c2], 0, 0, 0);
        }
    }

    if (wid < 2) {                                    // z columns (ct 0..3)
        #pragma unroll
        for (int c2 = 0; c2 < 2; ++c2) {
            int colg = (wid * 2 + c2) * 16 + nl;
            float bias = bz[colg];
            #pragma unroll
            for (int r = 0; r < 4; ++r) {
                int node = node0 + q * 4 + r;
                z[(size_t)node * C + colg] = fast_sigmoid(acc[c2][r] + bias);
            }
        }
    } else {                                          // r columns (ct 4..7)
        float dv[4];
        #pragma unroll
        for (int r = 0; r < 4; ++r) dv[r] = dinv[node0 + q * 4 + r];
        #pragma unroll
        for (int c2 = 0; c2 < 2; ++c2) {
            int oc = (wid * 2 + c2 - 4) * 16 + nl;
            float bias = br[oc];
            #pragma unroll
            for (int r = 0; r < 4; ++r) {
                int node = node0 + q * 4 + r;
                float sg = fast_sigmoid(acc[c2][r] + bias);
                float rhv = sg * bfu(hb[(size_t)node * C + oc]);
                rhb[(size_t)node * C + oc] = (unsigned short)f2bf(rhv);
                rhd8[(size_t)node * C + oc] =
                    (unsigned char)(fp8x2_enc(rhv * dv[r], 0.f) & 0xffu);
            }
        }
    }
}

// ======================= K5: fused prop1 + h-GEMM + GRU blend =======================
// Gather: 16 lanes cover one 64B fp8 row (uint = 4 ch) -> 1 cache line/edge;
// rhd8 table is 3.2MB -> per-XCD L2-resident.
__global__ __launch_bounds__(256) void prop_gemm_h_kernel(
        const int* __restrict__ cnt, const unsigned* __restrict__ csr,
        const float* __restrict__ dinv, const unsigned* __restrict__ rhd8,
        const unsigned short* __restrict__ xb, const unsigned short* __restrict__ rhb,
        const unsigned short* __restrict__ Pxb,
        const short* __restrict__ Bh, const float* __restrict__ bh,
        const float* __restrict__ z, const float* __restrict__ h,
        float* __restrict__ out) {
    __shared__ __align__(16) unsigned short lpr[16][72];
    int tid = threadIdx.x;
    int wid = __builtin_amdgcn_readfirstlane(tid >> 6);
    int lane = tid & 63;
    int lane15 = lane & 15;
    int g4 = lane >> 4;
    int node0 = blockIdx.x * 16;

    // ---- phase A: gather 4 nodes per wave (2 pair rounds) ----
    #pragma unroll
    for (int i = 0; i < 2; ++i) {
        int nlA = wid * 4 + i * 2;
        int nA = node0 + nlA;
        int2 cc = *(const int2*)(cnt + nA);
        int gqA = (min(cc.x, SLOTS) + 7) >> 3;
        int gqB = (min(cc.y, SLOTS) + 7) >> 3;
        const uint4* sA = (const uint4*)(csr + (size_t)nA * SLOTS);
        const uint4* sB = (const uint4*)(csr + (size_t)(nA + 1) * SLOTS);
        f32x4 aA = {0.f,0.f,0.f,0.f}, aB = {0.f,0.f,0.f,0.f};
        int gmax = max(gqA, gqB);
        for (int g = 0; g < gmax; ++g) {
            bool doA = g < gqA, doB = g < gqB;
            uint4 a0, a1, b0, b1;
            unsigned vA0, vA1, vB0, vB1;
            unsigned eA0, eA1, eB0, eB1;
            if (doA) { a0 = sA[2 * g]; a1 = sA[2 * g + 1]; }
            if (doB) { b0 = sB[2 * g]; b1 = sB[2 * g + 1]; }
            if (doA) {
                eA0 = sel4u(a0.x, a0.y, a0.z, a0.w, g4);
                eA1 = sel4u(a1.x, a1.y, a1.z, a1.w, g4);
                vA0 = rhd8[(size_t)(eA0 >> 16) * 16 + lane15];
                vA1 = rhd8[(size_t)(eA1 >> 16) * 16 + lane15];
            }
            if (doB) {
                eB0 = sel4u(b0.x, b0.y, b0.z, b0.w, g4);
                eB1 = sel4u(b1.x, b1.y, b1.z, b1.w, g4);
                vB0 = rhd8[(size_t)(eB0 >> 16) * 16 + lane15];
                vB1 = rhd8[(size_t)(eB1 >> 16) * 16 + lane15];
            }
            if (doA) {
                float w0 = bf_lo(eA0), w1 = bf_lo(eA1);
                f32x2 p;
                p = fp8x2_dec<0>(vA0); aA[0] = fmaf(w0, p[0], aA[0]); aA[1] = fmaf(w0, p[1], aA[1]);
                p = fp8x2_dec<1>(vA0); aA[2] = fmaf(w0, p[0], aA[2]); aA[3] = fmaf(w0, p[1], aA[3]);
                p = fp8x2_dec<0>(vA1); aA[0] = fmaf(w1, p[0], aA[0]); aA[1] = fmaf(w1, p[1], aA[1]);
                p = fp8x2_dec<1>(vA1); aA[2] = fmaf(w1, p[0], aA[2]); aA[3] = fmaf(w1, p[1], aA[3]);
            }
            if (doB) {
                float w0 = bf_lo(eB0), w1 = bf_lo(eB1);
                f32x2 p;
                p = fp8x2_dec<0>(vB0); aB[0] = fmaf(w0, p[0], aB[0]); aB[1] = fmaf(w0, p[1], aB[1]);
                p = fp8x2_dec<1>(vB0); aB[2] = fmaf(w0, p[0], aB[2]); aB[3] = fmaf(w0, p[1], aB[3]);
                p = fp8x2_dec<0>(vB1); aB[0] = fmaf(w1, p[0], aB[0]); aB[1] = fmaf(w1, p[1], aB[1]);
                p = fp8x2_dec<1>(vB1); aB[2] = fmaf(w1, p[0], aB[2]); aB[3] = fmaf(w1, p[1], aB[3]);
            }
        }
        #pragma unroll
        for (int j = 0; j < 4; ++j) {
            aA[j] += __shfl_xor(aA[j], 16, 64); aA[j] += __shfl_xor(aA[j], 32, 64);
            aB[j] += __shfl_xor(aB[j], 16, 64); aB[j] += __shfl_xor(aB[j], 32, 64);
        }
        float2 dvp = *(const float2*)(dinv + nA);
        if (g4 == 0) {
            float sA1 = -dvp.x, sB1 = -dvp.y;
            short4 prA = make_short4(f2bf(sA1 * aA[0]), f2bf(sA1 * aA[1]),
                                     f2bf(sA1 * aA[2]), f2bf(sA1 * aA[3]));
            short4 prB = make_short4(f2bf(sB1 * aB[0]), f2bf(sB1 * aB[1]),
                                     f2bf(sB1 * aB[2]), f2bf(sB1 * aB[3]));
            *(short4*)(&lpr[nlA][lane15 * 4]) = prA;
            *(short4*)(&lpr[nlA + 1][lane15 * 4]) = prB;
        }
    }
    __syncthreads();

    // ---- phase B: 16 nodes x 16 cols per wave (ct = wid) ----
    int q = lane >> 4;
    int nl = lane & 15;
    f32x4 acc = (f32x4){0.f, 0.f, 0.f, 0.f};
    const bf16x8* Bp = (const bf16x8*)Bh;
    #pragma unroll
    for (int kt = 0; kt < 8; ++kt) {
        bf16x8 a;
        if (kt < 6) {
            const unsigned short* src = (kt < 2) ? xb : (kt < 4) ? rhb : Pxb;
            a = *(const bf16x8*)(src + (size_t)(node0 + nl) * C + (kt & 1) * 32 + q * 8);
        } else {
            a = *(const bf16x8*)(&lpr[0][0] + nl * 72 + (kt & 1) * 32 + q * 8);
        }
        bf16x8 bfr = Bp[(kt * 4 + wid) * 64 + lane];
        acc = __builtin_amdgcn_mfma_f32_16x16x32_bf16(a, bfr, acc, 0, 0, 0);
    }

    int oc = wid * 16 + nl;
    float bias = bh[oc];
    #pragma unroll
    for (int r = 0; r < 4; ++r) {
        int node = node0 + q * 4 + r;
        float ht = fast_tanh(acc[r] + bias);
        float zz = z[(size_t)node * C + oc];
        float hv = h[(size_t)node * C + oc];   // fp32 h for final blend accuracy
        out[(size_t)node * C + oc] = (1.f - zz) * hv + zz * ht;
    }
}

extern "C" void kernel_launch(void* const* d_in, const int* in_sizes, int n_in,
                              void* d_out, int out_size, void* d_ws, size_t ws_size,
                              hipStream_t stream) {
    const float* x    = (const float*)d_in[0];
    const int*   eidx = (const int*)  d_in[1];
    const float* w    = (const float*)d_in[2];
    const float* h    = (const float*)d_in[3];
    const float* Wz   = (const float*)d_in[4];
    const float* bz   = (const float*)d_in[5];
    const float* Wr   = (const float*)d_in[6];
    const float* br   = (const float*)d_in[7];
    const float* Wh   = (const float*)d_in[8];
    const float* bh   = (const float*)d_in[9];
    float* out = (float*)d_out;
    float* ws  = (float*)d_ws;

    const int* row = eidx;
    const int* col = eidx + N_EDGES;

    int*            gcur = (int*)(ws + OFF_GCUR);
    float*          dinv = ws + OFF_DINV;
    int*            cnt  = (int*)(ws + OFF_CNT);
    unsigned*       csr  = (unsigned*)(ws + OFF_CSR);
    short*          Bzr  = (short*)(ws + OFF_BZR);
    short*          Bh   = (short*)(ws + OFF_BH);
    unsigned*       xh8  = (unsigned*)(ws + OFF_XH8);
    unsigned short* xb   = (unsigned short*)(ws + OFF_XB);
    unsigned short* hb   = (unsigned short*)(ws + OFF_HB);
    unsigned short* Pxb  = (unsigned short*)(ws + OFF_PXB);
    unsigned short* rhb  = (unsigned short*)(ws + OFF_RHB);
    unsigned char*  rhd8 = (unsigned char*)(ws + OFF_RHD8);
    uint2*          stg  = (uint2*)(ws + OFF_STG);            // aliases Pxb+rhb
    float*          z    = out;                  // z lives in d_out until gemm_h

    // K1: pack weights + zero gcur
    zero_pack_kernel<<<25, 256, 0, stream>>>(gcur, Wz, Wr, Wh, Bzr, Bh);

    // K2: stage edges into coarse buckets (coalesced run-writes)
    stage_kernel<<<STG_BLOCKS, 512, 0, stream>>>(row, col, w, gcur, stg);

    // K3: bucket-sort -> slot-CSR + cnt/dinv + xh8/xb/hb
    sort_kernel<<<NB, 256, 0, stream>>>(gcur, stg, x, h, csr, cnt, dinv, xh8, xb, hb);

    // K4: fused Lhat@[x|h] gather (fp8 table) + zr GEMM
    prop_gemm_zr_kernel<<<N_NODES / 16, 256, 0, stream>>>(
        cnt, csr, dinv, xh8, xb, hb, Bzr, bz, br, Pxb, z, rhb, rhd8);

    // K5: fused Lhat@(r*h) gather (fp8 table, L2-resident) + candidate GEMM + blend
    prop_gemm_h_kernel<<<N_NODES / 16, 256, 0, stream>>>(
        cnt, csr, dinv, (const unsigned*)rhd8, xb, rhb, Pxb, Bh, bh, z, h, out);
}

// Round 9
// 189.705 us; speedup vs baseline: 6.8672x; 1.0413x over previous
//
#include <hip/hip_runtime.h>
#include <cstdint>

#define N_NODES 50000
#define N_EDGES 800000
#define C 64
#define SLOTS 64                    // fixed CSR slots/node (deg~Bin: mean 16, max ~40)
#define B_N 120                     // nodes per coarse bucket
#define NB 417                      // ceil(N/B_N)
#define PCAP 2560                   // staging cap/bucket (mean 1918, ~14 sigma)
#define STG_BLOCKS 252
#define STG_CHUNK 3175              // 252*3175 >= E

typedef __attribute__((ext_vector_type(8))) short bf16x8;   // 8 bf16 in 4 VGPRs
typedef __attribute__((ext_vector_type(4))) float f32x4;
typedef __attribute__((ext_vector_type(2))) float f32x2;

// ---------------- workspace layout (word units) ----------------
// Round-20: occupancy fixes for stage (252 blocks) and sort (512 thr, pack
// blocks folded in); zr/h gather FMA packed to v_pk_fma_f32 pairs. Tables
// stay fp8 (R8, proven: FETCH halved, absmax 0.033 < 0.084).
static constexpr size_t OFF_GCUR = 0;                                // 512 ints
static constexpr size_t OFF_DINV = 512;                              // 50176 fl
static constexpr size_t OFF_CNT  = 50688;                            // 50176 ints
static constexpr size_t OFF_BZR  = 100864;                           // 16384 w
static constexpr size_t OFF_BH   = 117248;                           // 8192 w
static constexpr size_t OFF_CSR  = 125440;                           // N*64 uints = 3.2M w
static constexpr size_t OFF_XH8  = OFF_CSR + (size_t)N_NODES * 64;   // N*C*2B = 1.6M w
static constexpr size_t OFF_XB   = OFF_XH8 + (size_t)N_NODES * C / 2; // N*C ushort
static constexpr size_t OFF_HB   = OFF_XB + (size_t)N_NODES * C / 2;
static constexpr size_t OFF_PXB  = OFF_HB + (size_t)N_NODES * C / 2;
static constexpr size_t OFF_RHB  = OFF_PXB + (size_t)N_NODES * C / 2;
static constexpr size_t OFF_RHD8 = OFF_RHB + (size_t)N_NODES * C / 2; // N*C bytes = 0.8M w
// stg aliases PXB+RHB (3.2M w, both dead during staging): needs 2,135,040 w. OK.
static constexpr size_t OFF_STG  = OFF_PXB;
// end = OFF_RHD8 + N*C/4 = 12,125,440 words = 48.5 MB (< 64.5 MB proven OK)

__device__ __forceinline__ short f2bf(float f) {             // RNE fp32 -> bf16
    unsigned u = __float_as_uint(f);
    u += 0x7fffu + ((u >> 16) & 1u);
    return (short)(u >> 16);
}
__device__ __forceinline__ float bf_lo(unsigned v) { return __uint_as_float(v << 16); }
__device__ __forceinline__ float bf_hi(unsigned v) { return __uint_as_float(v & 0xffff0000u); }
__device__ __forceinline__ float bfu(unsigned short v) { return __uint_as_float((unsigned)v << 16); }
__device__ __forceinline__ float fast_sigmoid(float v) { return 1.f / (1.f + __expf(-v)); }
__device__ __forceinline__ float fast_tanh(float v) { return 1.f - 2.f / (__expf(2.f * v) + 1.f); }
__device__ __forceinline__ unsigned sel4u(unsigned a, unsigned b, unsigned c,
                                          unsigned d, int g) {
    unsigned r = (g & 1) ? b : a;
    unsigned s = (g & 1) ? d : c;
    return (g & 2) ? s : r;
}

// ---------------- fp8 e4m3 helpers (HW cvt on gfx950; manual fallback) ------
#if defined(__has_builtin)
#if __has_builtin(__builtin_amdgcn_cvt_pk_f32_fp8) && __has_builtin(__builtin_amdgcn_cvt_pk_fp8_f32)
#define HW_FP8 1
#endif
#endif

#ifndef HW_FP8
__device__ __forceinline__ float fp8_dec1(unsigned b) {      // e4m3fn -> f32
    unsigned s = b >> 7, e = (b >> 3) & 15u, m = b & 7u;
    float v = e ? __uint_as_float(((e + 120u) << 23) | (m << 20))
                : (float)m * 0.001953125f;                   // subnormal: m*2^-9
    return s ? -v : v;
}
__device__ __forceinline__ unsigned fp8_enc1(float f) {      // f32 -> e4m3fn RNE
    float a = fabsf(f);
    unsigned s = (__float_as_uint(f) >> 31) << 7;
    if (!(a < 448.f)) return s | 0x7e;
    int msub = (int)rintf(a * 512.f);
    if (msub <= 7) return s | (unsigned)msub;
    int e; float fr = frexpf(a, &e);
    int mm = (int)rintf(fr * 16.f);
    if (mm == 16) { mm = 8; e += 1; }
    int se = e - 1 + 7;
    if (se >= 16) return s | 0x7e;
    return s | (unsigned)(se << 3) | (unsigned)(mm - 8);
}
#endif

template <int HI>
__device__ __forceinline__ f32x2 fp8x2_dec(unsigned u) {     // bytes {2H,2H+1} -> 2 f32
#ifdef HW_FP8
    return __builtin_amdgcn_cvt_pk_f32_fp8(u, HI != 0);
#else
    f32x2 r;
    r[0] = fp8_dec1((u >> (HI * 16)) & 0xffu);
    r[1] = fp8_dec1((u >> (HI * 16 + 8)) & 0xffu);
    return r;
#endif
}
__device__ __forceinline__ unsigned fp8x2_enc(float a, float b) {  // low 16 bits
#ifdef HW_FP8
    return (unsigned)__builtin_amdgcn_cvt_pk_fp8_f32(a, b, 0, false) & 0xffffu;
#else
    return fp8_enc1(a) | (fp8_enc1(b) << 8);
#endif
}

// ======================= K1: zero gcur (1 block) =======================
__global__ __launch_bounds__(256) void zero_kernel(int* __restrict__ gcur) {
    gcur[threadIdx.x] = 0;
    gcur[256 + threadIdx.x] = 0;
}

// ======================= K2: stage edges into coarse buckets =======================
__global__ __launch_bounds__(512) void stage_kernel(
        const int* __restrict__ row, const int* __restrict__ col,
        const float* __restrict__ w,
        int* __restrict__ gcur, uint2* __restrict__ stg) {
    __shared__ int lcnt[NB];
    __shared__ int lbase[NB];
    int tid = threadIdx.x;
    int e0 = blockIdx.x * STG_CHUNK;
    int e1 = min(e0 + STG_CHUNK, N_EDGES);
    for (int i = tid; i < NB; i += 512) lcnt[i] = 0;
    __syncthreads();
    for (int e = e0 + tid; e < e1; e += 512)
        atomicAdd(&lcnt[row[e] / B_N], 1);
    __syncthreads();
    for (int i = tid; i < NB; i += 512) {
        int c = lcnt[i];
        lbase[i] = c ? atomicAdd(&gcur[i], c) : 0;
        lcnt[i] = 0;
    }
    __syncthreads();
    for (int e = e0 + tid; e < e1; e += 512) {
        int r = row[e];
        int b = r / B_N;
        int off = atomicAdd(&lcnt[b], 1);
        int pos = lbase[b] + off;
        unsigned cw = ((unsigned)col[e] << 16) | (unsigned short)f2bf(w[e]);
        if (pos < PCAP)
            stg[(size_t)b * PCAP + pos] = make_uint2((unsigned)(r - b * B_N), cw);
    }
}

// ======================= K3: bucket-sort + feature pack + weight pack =======
// Blocks [0,NB): slot-CSR build (512 thr halves serial passes). Blocks
// [NB,NB+12): weight pack for the GEMMs (independent work, fills the grid).
__global__ __launch_bounds__(512) void sort_kernel(
        const int* __restrict__ gcur, const uint2* __restrict__ stg,
        const float* __restrict__ x, const float* __restrict__ h,
        unsigned* __restrict__ csr, int* __restrict__ cnt, float* __restrict__ dinv,
        unsigned* __restrict__ xh8,
        unsigned short* __restrict__ xb, unsigned short* __restrict__ hb,
        const float* __restrict__ Wz, const float* __restrict__ Wr,
        const float* __restrict__ Wh,
        short* __restrict__ Bzr, short* __restrict__ Bh) {
    int b = blockIdx.x, tid = threadIdx.x;
    if (b >= NB) {                                    // ---- weight pack blocks ----
        int gid = (b - NB) * 512 + tid;               // < 6144
        if (gid < 4096) {                             // zr: 64 (kt,ct) x 64 lanes
            int ktct = gid >> 6, lane = gid & 63;
            int kt = ktct >> 3, ct = ktct & 7;
            int colg = ct * 16 + (lane & 15);
            int k0 = kt * 32 + (lane >> 4) * 8;
            const float* W = (colg < 64) ? Wz : Wr;
            int c = colg & 63;
            short v[8];
            #pragma unroll
            for (int j = 0; j < 8; ++j) {
                int k = k0 + j;
                v[j] = f2bf(W[(k >> 7) * (128 * 64) + (k & 127) * 64 + c]);
            }
            *(bf16x8*)(Bzr + (size_t)ktct * 512 + lane * 8) = *(bf16x8*)v;
        } else {                                      // h: 32 (kt,ct) x 64 lanes
            int idx = gid - 4096;
            int ktct = idx >> 6, lane = idx & 63;
            int kt = ktct >> 2, ct = ktct & 3;
            int colg = ct * 16 + (lane & 15);
            int k0 = kt * 32 + (lane >> 4) * 8;
            short v[8];
            #pragma unroll
            for (int j = 0; j < 8; ++j) {
                int k = k0 + j;
                v[j] = f2bf(Wh[(k >> 7) * (128 * 64) + (k & 127) * 64 + colg]);
            }
            *(bf16x8*)(Bh + (size_t)ktct * 512 + lane * 8) = *(bf16x8*)v;
        }
        return;
    }

    __shared__ int lcnt[B_N];
    __shared__ int lbase[B_N];
    __shared__ float ldeg[B_N];
    __shared__ float ldv[B_N];
    __shared__ int scanb[128];
    __shared__ unsigned lbuf[PCAP];
    __shared__ unsigned char lnode[PCAP];
    int n0 = b * B_N;
    int m = min(gcur[b], PCAP);
    for (int i = tid; i < B_N; i += 512) { lcnt[i] = 0; ldeg[i] = 0.f; }
    __syncthreads();
    const uint2* s = stg + (size_t)b * PCAP;
    for (int i = tid; i < m; i += 512) {             // pass 1: per-node count + deg
        uint2 e = s[i];
        atomicAdd(&lcnt[e.x], 1);
        atomicAdd(&ldeg[e.x], bf_lo(e.y));
    }
    __syncthreads();
    if (tid < 128) scanb[tid] = (tid < B_N) ? lcnt[tid] : 0;   // inclusive scan (128)
    __syncthreads();
    for (int d = 1; d < 128; d <<= 1) {
        int v = 0;
        if (tid < 128 && tid >= d) v = scanb[tid - d];
        __syncthreads();
        if (tid < 128) scanb[tid] += v;
        __syncthreads();
    }
    if (tid < B_N) { lbase[tid] = scanb[tid] - lcnt[tid]; lcnt[tid] = 0; }
    __syncthreads();
    for (int i = tid; i < m; i += 512) {             // pass 2: LDS scatter (sorted)
        uint2 e = s[i];
        int off = atomicAdd(&lcnt[e.x], 1);
        int p = lbase[e.x] + off;
        lbuf[p] = e.y;
        lnode[p] = (unsigned char)e.x;
    }
    __syncthreads();
    for (int i = tid; i < m; i += 512) {             // stream out, coalesced per node
        int nl = lnode[i];
        int pos = i - lbase[nl];
        csr[(size_t)(n0 + nl) * SLOTS + pos] = lbuf[i];
    }
    // zero-fill csr tails to a multiple of 8 slots; ALWAYS at least one group
    for (int i = tid; i < B_N * 8; i += 512) {
        int nl = i >> 3;
        int node = n0 + nl;
        if (node >= N_NODES) continue;
        int mm = min(lcnt[nl], SLOTS);
        int pe = (mm + 7) & ~7;
        if (pe == 0) pe = 8;
        int idx = mm + (i & 7);
        if (idx < pe) csr[(size_t)node * SLOTS + idx] = 0u;
    }
    if (tid < B_N) {                                  // cnt + dinv
        int node = n0 + tid;
        if (node < N_NODES) {
            cnt[node] = lcnt[tid];
            float d = ldeg[tid];
            float dv = (d > 0.f) ? rsqrtf(d) : 0.f;
            dinv[node] = dv;
            ldv[tid] = dv;
        } else ldv[tid] = 0.f;
    }
    __syncthreads();
    for (int i = tid; i < B_N * 16; i += 512) {       // feature pack (float4 groups)
        int g = n0 * 16 + i;
        if (g >= N_NODES * 16) continue;
        float dv = ldv[i >> 4];
        float4 xv = ((const float4*)x)[g];
        float4 hv = ((const float4*)h)[g];
        // fp8 pair-pack (x*dinv, h*dinv) per channel: 4 ch -> 8 bytes
        unsigned p01 = fp8x2_enc(xv.x * dv, hv.x * dv) |
                       (fp8x2_enc(xv.y * dv, hv.y * dv) << 16);
        unsigned p23 = fp8x2_enc(xv.z * dv, hv.z * dv) |
                       (fp8x2_enc(xv.w * dv, hv.w * dv) << 16);
        ((uint2*)xh8)[g] = make_uint2(p01, p23);
        ((short4*)xb)[g] = make_short4(f2bf(xv.x), f2bf(xv.y), f2bf(xv.z), f2bf(xv.w));
        ((short4*)hb)[g] = make_short4(f2bf(hv.x), f2bf(hv.y), f2bf(hv.z), f2bf(hv.w));
    }
}

// ======================= K4: fused prop2 + zr-GEMM =======================
// Gather: 16 lanes cover one 128B fp8 row; (x,h) channel pairs accumulate in
// f32x2 -> v_pk_fma_f32 (half the FMA issue). HW fp8 decode.
__global__ __launch_bounds__(256) void prop_gemm_zr_kernel(
        const int* __restrict__ cnt, const unsigned* __restrict__ csr,
        const float* __restrict__ dinv, const unsigned* __restrict__ xh8,
        const unsigned short* __restrict__ xb, const unsigned short* __restrict__ hb,
        const short* __restrict__ Bzr,
        const float* __restrict__ bz, const float* __restrict__ br,
        unsigned short* __restrict__ Pxb,
        float* __restrict__ z, unsigned short* __restrict__ rhb,
        unsigned char* __restrict__ rhd8) {
    __shared__ __align__(16) unsigned short lpx[16][72];
    __shared__ __align__(16) unsigned short lph[16][72];
    int tid = threadIdx.x;
    int wid = __builtin_amdgcn_readfirstlane(tid >> 6);
    int lane = tid & 63;
    int lane15 = lane & 15;
    int g4 = lane >> 4;
    int node0 = blockIdx.x * 16;                      // 3125 blocks, exact

    // ---- phase A: gather 4 nodes per wave (2 pair rounds) ----
    #pragma unroll
    for (int i = 0; i < 2; ++i) {
        int nlA = wid * 4 + i * 2;
        int nA = node0 + nlA;
        int2 cc = *(const int2*)(cnt + nA);           // uniform -> s_load
        int gqA = (min(cc.x, SLOTS) + 7) >> 3;
        int gqB = (min(cc.y, SLOTS) + 7) >> 3;
        const uint4* sA = (const uint4*)(csr + (size_t)nA * SLOTS);
        const uint4* sB = (const uint4*)(csr + (size_t)(nA + 1) * SLOTS);
        f32x2 pA[4] = {{0.f,0.f},{0.f,0.f},{0.f,0.f},{0.f,0.f}};
        f32x2 pB[4] = {{0.f,0.f},{0.f,0.f},{0.f,0.f},{0.f,0.f}};
        int gmax = max(gqA, gqB);
        for (int g = 0; g < gmax; ++g) {
            bool doA = g < gqA, doB = g < gqB;        // wave-uniform
            uint4 a0, a1, b0, b1;
            uint2 vA0, vA1, vB0, vB1;
            unsigned eA0, eA1, eB0, eB1;
            if (doA) { a0 = sA[2 * g]; a1 = sA[2 * g + 1]; }
            if (doB) { b0 = sB[2 * g]; b1 = sB[2 * g + 1]; }
            if (doA) {
                eA0 = sel4u(a0.x, a0.y, a0.z, a0.w, g4);
                eA1 = sel4u(a1.x, a1.y, a1.z, a1.w, g4);
                vA0 = *(const uint2*)(xh8 + (size_t)(eA0 >> 16) * 32 + lane15 * 2);
                vA1 = *(const uint2*)(xh8 + (size_t)(eA1 >> 16) * 32 + lane15 * 2);
            }
            if (doB) {
                eB0 = sel4u(b0.x, b0.y, b0.z, b0.w, g4);
                eB1 = sel4u(b1.x, b1.y, b1.z, b1.w, g4);
                vB0 = *(const uint2*)(xh8 + (size_t)(eB0 >> 16) * 32 + lane15 * 2);
                vB1 = *(const uint2*)(xh8 + (size_t)(eB1 >> 16) * 32 + lane15 * 2);
            }
            if (doA) {
                float w0 = bf_lo(eA0), w1 = bf_lo(eA1);
                f32x2 w0v = {w0, w0}, w1v = {w1, w1};
                pA[0] += w0v * fp8x2_dec<0>(vA0.x);
                pA[1] += w0v * fp8x2_dec<1>(vA0.x);
                pA[2] += w0v * fp8x2_dec<0>(vA0.y);
                pA[3] += w0v * fp8x2_dec<1>(vA0.y);
                pA[0] += w1v * fp8x2_dec<0>(vA1.x);
                pA[1] += w1v * fp8x2_dec<1>(vA1.x);
                pA[2] += w1v * fp8x2_dec<0>(vA1.y);
                pA[3] += w1v * fp8x2_dec<1>(vA1.y);
            }
            if (doB) {
                float w0 = bf_lo(eB0), w1 = bf_lo(eB1);
                f32x2 w0v = {w0, w0}, w1v = {w1, w1};
                pB[0] += w0v * fp8x2_dec<0>(vB0.x);
                pB[1] += w0v * fp8x2_dec<1>(vB0.x);
                pB[2] += w0v * fp8x2_dec<0>(vB0.y);
                pB[3] += w0v * fp8x2_dec<1>(vB0.y);
                pB[0] += w1v * fp8x2_dec<0>(vB1.x);
                pB[1] += w1v * fp8x2_dec<1>(vB1.x);
                pB[2] += w1v * fp8x2_dec<0>(vB1.y);
                pB[3] += w1v * fp8x2_dec<1>(vB1.y);
            }
        }
        // butterfly reduce across the 4 lane-groups
        #pragma unroll
        for (int j = 0; j < 4; ++j) {
            pA[j][0] += __shfl_xor(pA[j][0], 16, 64); pA[j][0] += __shfl_xor(pA[j][0], 32, 64);
            pA[j][1] += __shfl_xor(pA[j][1], 16, 64); pA[j][1] += __shfl_xor(pA[j][1], 32, 64);
            pB[j][0] += __shfl_xor(pB[j][0], 16, 64); pB[j][0] += __shfl_xor(pB[j][0], 32, 64);
            pB[j][1] += __shfl_xor(pB[j][1], 16, 64); pB[j][1] += __shfl_xor(pB[j][1], 32, 64);
        }
        float2 dvp = *(const float2*)(dinv + nA);     // uniform
        if (g4 == 0) {                                // lanes 0..15 hold ch 4*l..4*l+3
            float sA1 = -dvp.x, sB1 = -dvp.y;
            short4 pxA = make_short4(f2bf(sA1 * pA[0][0]), f2bf(sA1 * pA[1][0]),
                                     f2bf(sA1 * pA[2][0]), f2bf(sA1 * pA[3][0]));
            short4 phA = make_short4(f2bf(sA1 * pA[0][1]), f2bf(sA1 * pA[1][1]),
                                     f2bf(sA1 * pA[2][1]), f2bf(sA1 * pA[3][1]));
            short4 pxB = make_short4(f2bf(sB1 * pB[0][0]), f2bf(sB1 * pB[1][0]),
                                     f2bf(sB1 * pB[2][0]), f2bf(sB1 * pB[3][0]));
            short4 phB = make_short4(f2bf(sB1 * pB[0][1]), f2bf(sB1 * pB[1][1]),
                                     f2bf(sB1 * pB[2][1]), f2bf(sB1 * pB[3][1]));
            *(short4*)(&lpx[nlA][lane15 * 4]) = pxA;
            *(short4*)(&lph[nlA][lane15 * 4]) = phA;
            *(short4*)(&lpx[nlA + 1][lane15 * 4]) = pxB;
            *(short4*)(&lph[nlA + 1][lane15 * 4]) = phB;
            *(short4*)(Pxb + (size_t)nA * C + lane15 * 4) = pxA;
            *(short4*)(Pxb + (size_t)(nA + 1) * C + lane15 * 4) = pxB;
        }
    }
    __syncthreads();

    // ---- phase B: 16 nodes x 32 cols per wave ----
    int q = lane >> 4;
    int nl = lane & 15;
    f32x4 acc[2];
    acc[0] = (f32x4){0.f, 0.f, 0.f, 0.f};
    acc[1] = (f32x4){0.f, 0.f, 0.f, 0.f};
    const bf16x8* Bp = (const bf16x8*)Bzr;
    #pragma unroll
    for (int kt = 0; kt < 8; ++kt) {
        bf16x8 a;
        if (kt < 4) {
            const unsigned short* src = (kt < 2) ? xb : hb;
            a = *(const bf16x8*)(src + (size_t)(node0 + nl) * C + (kt & 1) * 32 + q * 8);
        } else {
            const unsigned short* src = (kt < 6) ? &lpx[0][0] : &lph[0][0];
            a = *(const bf16x8*)(src + nl * 72 + (kt & 1) * 32 + q * 8);
        }
        #pragma unroll
        for (int c2 = 0; c2 < 2; ++c2) {
            int ct = wid * 2 + c2;
            bf16x8 bfr = Bp[(kt * 8 + ct) * 64 + lane];
            acc[c2] = __builtin_amdgcn_mfma_f32_16x16x32_bf16(a, bfr, acc[c2], 0, 0, 0);
        }
    }

    if (wid < 2) {                                    // z columns (ct 0..3)
        #pragma unroll
        for (int c2 = 0; c2 < 2; ++c2) {
            int colg = (wid * 2 + c2) * 16 + nl;
            float bias = bz[colg];
            #pragma unroll
            for (int r = 0; r < 4; ++r) {
                int node = node0 + q * 4 + r;
                z[(size_t)node * C + colg] = fast_sigmoid(acc[c2][r] + bias);
            }
        }
    } else {                                          // r columns (ct 4..7)
        float dv[4];
        #pragma unroll
        for (int r = 0; r < 4; ++r) dv[r] = dinv[node0 + q * 4 + r];
        #pragma unroll
        for (int c2 = 0; c2 < 2; ++c2) {
            int oc = (wid * 2 + c2 - 4) * 16 + nl;
            float bias = br[oc];
            #pragma unroll
            for (int r = 0; r < 4; ++r) {
                int node = node0 + q * 4 + r;
                float sg = fast_sigmoid(acc[c2][r] + bias);
                float rhv = sg * bfu(hb[(size_t)node * C + oc]);
                rhb[(size_t)node * C + oc] = (unsigned short)f2bf(rhv);
                rhd8[(size_t)node * C + oc] =
                    (unsigned char)(fp8x2_enc(rhv * dv[r], 0.f) & 0xffu);
            }
        }
    }
}

// ======================= K5: fused prop1 + h-GEMM + GRU blend =======================
// Gather: 16 lanes cover one 64B fp8 row -> 1 line/edge; table L2-resident.
// Channel-pair accumulators in f32x2 -> v_pk_fma_f32.
__global__ __launch_bounds__(256) void prop_gemm_h_kernel(
        const int* __restrict__ cnt, const unsigned* __restrict__ csr,
        const float* __restrict__ dinv, const unsigned* __restrict__ rhd8,
        const unsigned short* __restrict__ xb, const unsigned short* __restrict__ rhb,
        const unsigned short* __restrict__ Pxb,
        const short* __restrict__ Bh, const float* __restrict__ bh,
        const float* __restrict__ z, const float* __restrict__ h,
        float* __restrict__ out) {
    __shared__ __align__(16) unsigned short lpr[16][72];
    int tid = threadIdx.x;
    int wid = __builtin_amdgcn_readfirstlane(tid >> 6);
    int lane = tid & 63;
    int lane15 = lane & 15;
    int g4 = lane >> 4;
    int node0 = blockIdx.x * 16;

    // ---- phase A: gather 4 nodes per wave (2 pair rounds) ----
    #pragma unroll
    for (int i = 0; i < 2; ++i) {
        int nlA = wid * 4 + i * 2;
        int nA = node0 + nlA;
        int2 cc = *(const int2*)(cnt + nA);
        int gqA = (min(cc.x, SLOTS) + 7) >> 3;
        int gqB = (min(cc.y, SLOTS) + 7) >> 3;
        const uint4* sA = (const uint4*)(csr + (size_t)nA * SLOTS);
        const uint4* sB = (const uint4*)(csr + (size_t)(nA + 1) * SLOTS);
        f32x2 pA[2] = {{0.f,0.f},{0.f,0.f}};          // ch pairs (0,1),(2,3)
        f32x2 pB[2] = {{0.f,0.f},{0.f,0.f}};
        int gmax = max(gqA, gqB);
        for (int g = 0; g < gmax; ++g) {
            bool doA = g < gqA, doB = g < gqB;
            uint4 a0, a1, b0, b1;
            unsigned vA0, vA1, vB0, vB1;
            unsigned eA0, eA1, eB0, eB1;
            if (doA) { a0 = sA[2 * g]; a1 = sA[2 * g + 1]; }
            if (doB) { b0 = sB[2 * g]; b1 = sB[2 * g + 1]; }
            if (doA) {
                eA0 = sel4u(a0.x, a0.y, a0.z, a0.w, g4);
                eA1 = sel4u(a1.x, a1.y, a1.z, a1.w, g4);
                vA0 = rhd8[(size_t)(eA0 >> 16) * 16 + lane15];
                vA1 = rhd8[(size_t)(eA1 >> 16) * 16 + lane15];
            }
            if (doB) {
                eB0 = sel4u(b0.x, b0.y, b0.z, b0.w, g4);
                eB1 = sel4u(b1.x, b1.y, b1.z, b1.w, g4);
                vB0 = rhd8[(size_t)(eB0 >> 16) * 16 + lane15];
                vB1 = rhd8[(size_t)(eB1 >> 16) * 16 + lane15];
            }
            if (doA) {
                float w0 = bf_lo(eA0), w1 = bf_lo(eA1);
                f32x2 w0v = {w0, w0}, w1v = {w1, w1};
                pA[0] += w0v * fp8x2_dec<0>(vA0);
                pA[1] += w0v * fp8x2_dec<1>(vA0);
                pA[0] += w1v * fp8x2_dec<0>(vA1);
                pA[1] += w1v * fp8x2_dec<1>(vA1);
            }
            if (doB) {
                float w0 = bf_lo(eB0), w1 = bf_lo(eB1);
                f32x2 w0v = {w0, w0}, w1v = {w1, w1};
                pB[0] += w0v * fp8x2_dec<0>(vB0);
                pB[1] += w0v * fp8x2_dec<1>(vB0);
                pB[0] += w1v * fp8x2_dec<0>(vB1);
                pB[1] += w1v * fp8x2_dec<1>(vB1);
            }
        }
        #pragma unroll
        for (int j = 0; j < 2; ++j) {
            pA[j][0] += __shfl_xor(pA[j][0], 16, 64); pA[j][0] += __shfl_xor(pA[j][0], 32, 64);
            pA[j][1] += __shfl_xor(pA[j][1], 16, 64); pA[j][1] += __shfl_xor(pA[j][1], 32, 64);
            pB[j][0] += __shfl_xor(pB[j][0], 16, 64); pB[j][0] += __shfl_xor(pB[j][0], 32, 64);
            pB[j][1] += __shfl_xor(pB[j][1], 16, 64); pB[j][1] += __shfl_xor(pB[j][1], 32, 64);
        }
        float2 dvp = *(const float2*)(dinv + nA);
        if (g4 == 0) {
            float sA1 = -dvp.x, sB1 = -dvp.y;
            short4 prA = make_short4(f2bf(sA1 * pA[0][0]), f2bf(sA1 * pA[0][1]),
                                     f2bf(sA1 * pA[1][0]), f2bf(sA1 * pA[1][1]));
            short4 prB = make_short4(f2bf(sB1 * pB[0][0]), f2bf(sB1 * pB[0][1]),
                                     f2bf(sB1 * pB[1][0]), f2bf(sB1 * pB[1][1]));
            *(short4*)(&lpr[nlA][lane15 * 4]) = prA;
            *(short4*)(&lpr[nlA + 1][lane15 * 4]) = prB;
        }
    }
    __syncthreads();

    // ---- phase B: 16 nodes x 16 cols per wave (ct = wid) ----
    int q = lane >> 4;
    int nl = lane & 15;
    f32x4 acc = (f32x4){0.f, 0.f, 0.f, 0.f};
    const bf16x8* Bp = (const bf16x8*)Bh;
    #pragma unroll
    for (int kt = 0; kt < 8; ++kt) {
        bf16x8 a;
        if (kt < 6) {
            const unsigned short* src = (kt < 2) ? xb : (kt < 4) ? rhb : Pxb;
            a = *(const bf16x8*)(src + (size_t)(node0 + nl) * C + (kt & 1) * 32 + q * 8);
        } else {
            a = *(const bf16x8*)(&lpr[0][0] + nl * 72 + (kt & 1) * 32 + q * 8);
        }
        bf16x8 bfr = Bp[(kt * 4 + wid) * 64 + lane];
        acc = __builtin_amdgcn_mfma_f32_16x16x32_bf16(a, bfr, acc, 0, 0, 0);
    }

    int oc = wid * 16 + nl;
    float bias = bh[oc];
    #pragma unroll
    for (int r = 0; r < 4; ++r) {
        int node = node0 + q * 4 + r;
        float ht = fast_tanh(acc[r] + bias);
        float zz = z[(size_t)node * C + oc];
        float hv = h[(size_t)node * C + oc];   // fp32 h for final blend accuracy
        out[(size_t)node * C + oc] = (1.f - zz) * hv + zz * ht;
    }
}

extern "C" void kernel_launch(void* const* d_in, const int* in_sizes, int n_in,
                              void* d_out, int out_size, void* d_ws, size_t ws_size,
                              hipStream_t stream) {
    const float* x    = (const float*)d_in[0];
    const int*   eidx = (const int*)  d_in[1];
    const float* w    = (const float*)d_in[2];
    const float* h    = (const float*)d_in[3];
    const float* Wz   = (const float*)d_in[4];
    const float* bz   = (const float*)d_in[5];
    const float* Wr   = (const float*)d_in[6];
    const float* br   = (const float*)d_in[7];
    const float* Wh   = (const float*)d_in[8];
    const float* bh   = (const float*)d_in[9];
    float* out = (float*)d_out;
    float* ws  = (float*)d_ws;

    const int* row = eidx;
    const int* col = eidx + N_EDGES;

    int*            gcur = (int*)(ws + OFF_GCUR);
    float*          dinv = ws + OFF_DINV;
    int*            cnt  = (int*)(ws + OFF_CNT);
    unsigned*       csr  = (unsigned*)(ws + OFF_CSR);
    short*          Bzr  = (short*)(ws + OFF_BZR);
    short*          Bh   = (short*)(ws + OFF_BH);
    unsigned*       xh8  = (unsigned*)(ws + OFF_XH8);
    unsigned short* xb   = (unsigned short*)(ws + OFF_XB);
    unsigned short* hb   = (unsigned short*)(ws + OFF_HB);
    unsigned short* Pxb  = (unsigned short*)(ws + OFF_PXB);
    unsigned short* rhb  = (unsigned short*)(ws + OFF_RHB);
    unsigned char*  rhd8 = (unsigned char*)(ws + OFF_RHD8);
    uint2*          stg  = (uint2*)(ws + OFF_STG);            // aliases Pxb+rhb
    float*          z    = out;                  // z lives in d_out until gemm_h

    // K1: zero gcur
    zero_kernel<<<1, 256, 0, stream>>>(gcur);

    // K2: stage edges into coarse buckets (252 blocks -> 2x occupancy)
    stage_kernel<<<STG_BLOCKS, 512, 0, stream>>>(row, col, w, gcur, stg);

    // K3: bucket-sort (512 thr) + feature pack + weight pack (12 extra blocks)
    sort_kernel<<<NB + 12, 512, 0, stream>>>(gcur, stg, x, h, csr, cnt, dinv,
                                             xh8, xb, hb, Wz, Wr, Wh, Bzr, Bh);

    // K4: fused Lhat@[x|h] gather (fp8 table) + zr GEMM
    prop_gemm_zr_kernel<<<N_NODES / 16, 256, 0, stream>>>(
        cnt, csr, dinv, xh8, xb, hb, Bzr, bz, br, Pxb, z, rhb, rhd8);

    // K5: fused Lhat@(r*h) gather (fp8 table, L2-resident) + candidate GEMM + blend
    prop_gemm_h_kernel<<<N_NODES / 16, 256, 0, stream>>>(
        cnt, csr, dinv, (const unsigned*)rhd8, xb, rhb, Pxb, Bh, bh, z, h, out);
}